// Round 13
// baseline (494.062 us; speedup 1.0000x reference)
//
#include <hip/hip_runtime.h>
#include <cstdint>
#include <cstddef>

#define NU 100000
#define NI 50000
#define NTOT 150000
#define EDIM 64
#define NE 1000000
#define NLAYERS 3
#define NTILES (NTOT / 16)                            // 9375
#define NPAIR (NTOT / 2)                              // 75000 (gather: 2 rows/wave)

// ---- binned CSR build (two-level: LDS stage -> contiguous global chunks) ----
#define NBKT 256
#define NPB 586                    // nodes per bucket (256*586 = 150016 >= NTOT)
#define BCAP 13312                 // packed pairs per bucket; max expected ~12.1K
#define BCUR_STRIDE 16             // u32s -> 64B per cursor line
#define BIN_EPB 1024               // edges per binpairs block
#define BIN_NBLK ((NE + BIN_EPB - 1) / BIN_EPB)       // 977
#define LCAP 28                    // LDS pairs per bucket
#define LPAD 29                    // +1 pad -> conflict-free flush
#define SLICE_CAP 13312            // ints; max bucket pair-count ~12.1K

typedef __attribute__((ext_vector_type(8))) short short8;   // 8 bf16 (4 VGPRs)
typedef __attribute__((ext_vector_type(4))) float floatx4;  // 4 fp32 acc

// ---------------- bf16 helpers (raw-bit, RNE) ----------------
__device__ inline unsigned short f2bf(float f) {
    unsigned u = __float_as_uint(f);
    u += 0x7fffu + ((u >> 16) & 1u);
    return (unsigned short)(u >> 16);
}
__device__ inline unsigned pack_bf2(float a, float b) {
    unsigned ua = __float_as_uint(a); ua += 0x7fffu + ((ua >> 16) & 1u);
    unsigned ub = __float_as_uint(b); ub += 0x7fffu + ((ub >> 16) & 1u);
    return (ua >> 16) | (ub & 0xffff0000u);
}
__device__ inline float bf_lo(unsigned u) { return __uint_as_float(u << 16); }
__device__ inline float bf_hi(unsigned u) { return __uint_as_float(u & 0xffff0000u); }

// ---------------- phase A: two-level binning of packed (local,other) ----------------
// Pair word = (node - bucket*NPB) << 18 | other. LDS-staged per block, flushed
// as contiguous chunks (round-9 verified: this is the scatter-write fix).
__global__ __launch_bounds__(256) void k_binpairs(const int* __restrict__ eu,
                                                  const int* __restrict__ ei,
                                                  unsigned* __restrict__ bcur,
                                                  unsigned* __restrict__ bbuf) {
    __shared__ unsigned lbuf[NBKT * LPAD];   // 29.7 KB
    __shared__ int lcnt[NBKT];
    int t = threadIdx.x;
    if (t < NBKT) lcnt[t] = 0;
    __syncthreads();
    int ebase = blockIdx.x * BIN_EPB + t;
#pragma unroll
    for (int k = 0; k < 4; ++k) {
        int e = ebase + k * 256;
        if (e < NE) {
            int u = eu[e];
            int v = NU + ei[e];
            int b0 = u / NPB;
            int w0 = ((u - b0 * NPB) << 18) | v;
            int p0 = atomicAdd(&lcnt[b0], 1);
            if (p0 < LCAP) lbuf[b0 * LPAD + p0] = (unsigned)w0;
            else {
                unsigned gp = atomicAdd(&bcur[b0 * BCUR_STRIDE], 1u);
                if (gp < BCAP) bbuf[(size_t)b0 * BCAP + gp] = (unsigned)w0;
            }
            int b1 = v / NPB;
            int w1 = ((v - b1 * NPB) << 18) | u;
            int p1 = atomicAdd(&lcnt[b1], 1);
            if (p1 < LCAP) lbuf[b1 * LPAD + p1] = (unsigned)w1;
            else {
                unsigned gp = atomicAdd(&bcur[b1 * BCUR_STRIDE], 1u);
                if (gp < BCAP) bbuf[(size_t)b1 * BCAP + gp] = (unsigned)w1;
            }
        }
    }
    __syncthreads();
    // flush: thread t owns bucket t; one reservation, sequential chunk write
    int nb = min(lcnt[t], LCAP);
    if (nb > 0) {
        unsigned gp = atomicAdd(&bcur[t * BCUR_STRIDE], (unsigned)nb);
        for (int i = 0; i < nb; ++i) {
            unsigned idx = gp + i;
            if (idx < BCAP) bbuf[(size_t)t * BCAP + idx] = lbuf[t * LPAD + i];
        }
    }
}

// ---------------- phase B: per-bucket build (fused: prefix + deg/scan/CSR +
// init + W-conv + sentinel zero + degree-sorted pairing perm). One block per
// bucket. NEW (round 13): block-local counting sort of the bucket's nodes by
// degree into perm[] -> gather waves pair rows of (near-)equal degree,
// eliminating the max(dg0,dg1) padding waste.
__global__ __launch_bounds__(1024) void k_buildcsr(
    const unsigned* __restrict__ bbuf, const unsigned* __restrict__ bcur,
    int* __restrict__ deg, int* __restrict__ start,
    float* __restrict__ isq, float* __restrict__ inv, int* __restrict__ csr,
    const float* __restrict__ ue, const float* __restrict__ ie,
    unsigned* __restrict__ snap0, unsigned* __restrict__ gbuf,
    unsigned* __restrict__ Ebuf,
    const float* __restrict__ Wg, const float* __restrict__ Wb,
    unsigned short* __restrict__ wgb, unsigned short* __restrict__ wbb,
    int* __restrict__ perm) {
    __shared__ int slice[SLICE_CAP];   // prefix temp, scan temp, then csr slice
    __shared__ int lcur[NPB];          // per-node count, cursor, then 64 deg bins
    __shared__ float sisq[NPB];
    __shared__ int bb_s, scnt_s;
    int b = blockIdx.x;
    int t = threadIdx.x;
    int n0 = b * NPB;
    int nn = NTOT - n0;
    if (nn > NPB) nn = NPB;
    if (nn < 0) nn = 0;
    // bucket-total prefix (redundant per block; 256 values, trivial)
    if (t < NBKT) slice[t] = min((int)bcur[t * BCUR_STRIDE], BCAP);
    if (t < NPB) lcur[t] = 0;
    __syncthreads();
    for (int off = 1; off < NBKT; off <<= 1) {
        int tmp = (t < NBKT && t >= off) ? slice[t - off] : 0;
        __syncthreads();
        if (t < NBKT) slice[t] += tmp;
        __syncthreads();
    }
    if (t == 0) {
        int tb = min((int)bcur[b * BCUR_STRIDE], BCAP);
        scnt_s = tb;
        bb_s = slice[b] - tb;   // exclusive prefix for this bucket
    }
    __syncthreads();
    int c = scnt_s;
    int bb = bb_s;
    const unsigned* pb = bbuf + (size_t)b * BCAP;
    // count pass
    for (int i = t; i < c; i += 1024) atomicAdd(&lcur[(int)(pb[i] >> 18)], 1);
    __syncthreads();
    // exclusive scan over nn counts (1024-wide Hillis-Steele in slice[])
    int cnt_t = (t < nn) ? lcur[t] : 0;
    slice[t] = cnt_t;
    __syncthreads();
    for (int off = 1; off < 1024; off <<= 1) {
        int tmp = (t >= off) ? slice[t - off] : 0;
        __syncthreads();
        slice[t] += tmp;
        __syncthreads();
    }
    int excl = slice[t] - cnt_t;
    int slen = slice[1023];            // total pairs in bucket
    if (t < nn) {
        int n = n0 + t;
        deg[n] = cnt_t;
        start[n] = bb + excl;
        float df = (float)cnt_t;
        float q = cnt_t > 0 ? 1.0f / sqrtf(df) : 0.f;
        isq[n] = q;
        sisq[t] = q;
        inv[n] = cnt_t > 0 ? 1.0f / df : 0.f;
    }
    __syncthreads();                   // everyone done reading slice & lcur
    if (t < nn) lcur[t] = excl;        // reuse as placement cursor
    __syncthreads();
    // place pass
    for (int i = t; i < c; i += 1024) {
        unsigned pr = pb[i];
        int idx = atomicAdd(&lcur[(int)(pr >> 18)], 1);
        if (idx < SLICE_CAP) slice[idx] = (int)(pr & 0x3FFFFu);
    }
    __syncthreads();
    if (slen > SLICE_CAP) slen = SLICE_CAP;
    for (int i = t; i < slen; i += 1024) csr[bb + i] = slice[i];
    // ---- degree-sorted pairing permutation (block-local counting sort) ----
    __syncthreads();                   // lcur free (place pass done)
    if (t < 64) lcur[t] = 0;
    __syncthreads();
    int mybin = -1, myrank = 0;
    if (t < nn) {
        mybin = cnt_t < 63 ? cnt_t : 63;
        myrank = atomicAdd(&lcur[mybin], 1);
    }
    __syncthreads();
    if (t == 0) {
        int s = 0;
        for (int q = 0; q < 64; ++q) { int cc = lcur[q]; lcur[q] = s; s += cc; }
    }
    __syncthreads();
    if (t < nn) perm[n0 + lcur[mybin] + myrank] = n0 + t;
    // fused init: this bucket's rows -> snap0 (bf16) + gbuf (embS = isq*emb)
    for (int idx = t; idx < nn * 16; idx += 1024) {
        int r = idx >> 4, cc = idx & 15;
        int n = n0 + r;
        float4 v = (n < NU) ? ((const float4*)ue)[(size_t)n * 16 + cc]
                            : ((const float4*)ie)[(size_t)(n - NU) * 16 + cc];
        float s = sisq[r];
        uint2 bq, bs;
        bq.x = pack_bf2(v.x, v.y);
        bq.y = pack_bf2(v.z, v.w);
        bs.x = pack_bf2(v.x * s, v.y * s);
        bs.y = pack_bf2(v.z * s, v.w * s);
        ((uint2*)snap0)[(size_t)n * 16 + cc] = bq;
        ((uint2*)gbuf)[(size_t)n * 16 + cc] = bs;
    }
    // W conversion + sentinel-row zero: block 0 only
    if (b == 0) {
        for (int i = t; i < NLAYERS * 4096 / 4; i += 1024) {
            float4 g4 = ((const float4*)Wg)[i];
            float4 b4 = ((const float4*)Wb)[i];
            uint2 g, bq;
            g.x = pack_bf2(g4.x, g4.y); g.y = pack_bf2(g4.z, g4.w);
            bq.x = pack_bf2(b4.x, b4.y); bq.y = pack_bf2(b4.z, b4.w);
            ((uint2*)wgb)[i] = g;
            ((uint2*)wbb)[i] = bq;
        }
        if (t < 16) {
            ((uint2*)(Ebuf + NTOT * 32))[t] = make_uint2(0u, 0u);
            ((uint2*)(gbuf + NTOT * 32))[t] = make_uint2(0u, 0u);
        }
    }
}

// ---------------- sparse gather (pull), bf16 rows, wide loads ----------------
// v6: rows taken via degree-sorted perm (pairs have equal degree -> dgmax ==
// dg, no pair-max waste) + quantum-4 tail loop (slot padding ceil-4 not
// ceil-16). Per-lane accumulation subsequence identical to v5; dropped
// sentinel slots were exact +0.0f -> bit-identical output.
__global__ __launch_bounds__(256) void k_gather(
    const unsigned* __restrict__ in_bf, unsigned* __restrict__ out_bf,
    const int* __restrict__ csr, const int* __restrict__ start,
    const int* __restrict__ deg, const float* __restrict__ sA,
    const int* __restrict__ perm) {
    int gw = (blockIdx.x * 256 + threadIdx.x) >> 6;   // wave id = row pair
    int lane = threadIdx.x & 63;
    if (gw >= NPAIR) return;
    int l2 = lane & 31;
    int hbase = lane & 32;                 // 0 or 32: this half's lane base
    int row = perm[gw * 2 + (lane >> 5)];  // degree-matched pairing
    int s = l2 & 7;                        // dword-quad owner (16B of the row)
    int g = l2 >> 3;                       // neighbor slot within batch (0..3)
    int s0 = start[row];
    int dg = deg[row];
    float sc = sA[row];                    // hoisted
    int dgo = __shfl_xor(dg, 32);          // other half's degree (== dg mostly)
    int dgmax = max(dg, dgo);              // uniform across the wave
    float aL0 = 0.f, aL1 = 0.f, aL2 = 0.f, aL3 = 0.f;
    float aH0 = 0.f, aH1 = 0.f, aH2 = 0.f, aH3 = 0.f;
    for (int j0 = 0; j0 < dgmax; j0 += 32) {
        int nidx = NTOT;                   // sentinel zero row
        if (j0 + l2 < dg) nidx = csr[s0 + j0 + l2];
        int jlim = min(32, dgmax - j0);
        int j = 0;
        for (; j + 16 <= jlim; j += 16) {
            // groups cover slots j..j+15 exactly once: j+4k+g, k=0..3
            int m0 = __shfl(nidx, hbase + j + g);
            int m1 = __shfl(nidx, hbase + j + 4 + g);
            int m2 = __shfl(nidx, hbase + j + 8 + g);
            int m3 = __shfl(nidx, hbase + j + 12 + g);
            uint4 u0 = *(const uint4*)(in_bf + (size_t)m0 * 32 + s * 4);
            uint4 u1 = *(const uint4*)(in_bf + (size_t)m1 * 32 + s * 4);
            uint4 u2 = *(const uint4*)(in_bf + (size_t)m2 * 32 + s * 4);
            uint4 u3 = *(const uint4*)(in_bf + (size_t)m3 * 32 + s * 4);
            aL0 += bf_lo(u0.x); aH0 += bf_hi(u0.x);
            aL1 += bf_lo(u0.y); aH1 += bf_hi(u0.y);
            aL2 += bf_lo(u0.z); aH2 += bf_hi(u0.z);
            aL3 += bf_lo(u0.w); aH3 += bf_hi(u0.w);
            aL0 += bf_lo(u1.x); aH0 += bf_hi(u1.x);
            aL1 += bf_lo(u1.y); aH1 += bf_hi(u1.y);
            aL2 += bf_lo(u1.z); aH2 += bf_hi(u1.z);
            aL3 += bf_lo(u1.w); aH3 += bf_hi(u1.w);
            aL0 += bf_lo(u2.x); aH0 += bf_hi(u2.x);
            aL1 += bf_lo(u2.y); aH1 += bf_hi(u2.y);
            aL2 += bf_lo(u2.z); aH2 += bf_hi(u2.z);
            aL3 += bf_lo(u2.w); aH3 += bf_hi(u2.w);
            aL0 += bf_lo(u3.x); aH0 += bf_hi(u3.x);
            aL1 += bf_lo(u3.y); aH1 += bf_hi(u3.y);
            aL2 += bf_lo(u3.z); aH2 += bf_hi(u3.z);
            aL3 += bf_lo(u3.w); aH3 += bf_hi(u3.w);
        }
        for (; j < jlim; j += 4) {         // quantum-4 tail (j <= 28, +g <= 31)
            int m0 = __shfl(nidx, hbase + j + g);
            uint4 u0 = *(const uint4*)(in_bf + (size_t)m0 * 32 + s * 4);
            aL0 += bf_lo(u0.x); aH0 += bf_hi(u0.x);
            aL1 += bf_lo(u0.y); aH1 += bf_hi(u0.y);
            aL2 += bf_lo(u0.z); aH2 += bf_hi(u0.z);
            aL3 += bf_lo(u0.w); aH3 += bf_hi(u0.w);
        }
    }
    // reduce the 4 group partials (lane bits 3 and 4; stays within the half)
#pragma unroll
    for (int m = 8; m <= 16; m <<= 1) {
        aL0 += __shfl_xor(aL0, m); aH0 += __shfl_xor(aH0, m);
        aL1 += __shfl_xor(aL1, m); aH1 += __shfl_xor(aH1, m);
        aL2 += __shfl_xor(aL2, m); aH2 += __shfl_xor(aH2, m);
        aL3 += __shfl_xor(aL3, m); aH3 += __shfl_xor(aH3, m);
    }
    if (g == 0) {
        uint4 o;
        o.x = pack_bf2(sc * aL0, sc * aH0);
        o.y = pack_bf2(sc * aL1, sc * aH1);
        o.z = pack_bf2(sc * aL2, sc * aH2);
        o.w = pack_bf2(sc * aL3, sc * aH3);
        *(uint4*)(out_bf + (size_t)row * 32 + s * 4) = o;
    }
}

// ---------------- dense per-row update via MFMA (all-bf16 state) ----------------
// One wave per 16-row tile. Reads g rows (from gbuf) + a rows (snap_prev).
// writeScaled: also write embS = isq*emb bf16 IN PLACE over gbuf. finalOut:
// fuse the output mean instead of writing snap_l. gbuf NOT __restrict__.
__global__ __launch_bounds__(256) void k_dense_mfma(
    const unsigned short* __restrict__ a_prev, unsigned* gbuf,
    unsigned short* __restrict__ snap_l, const float* __restrict__ isq,
    const unsigned short* __restrict__ wgb, const unsigned short* __restrict__ wbb,
    const float* __restrict__ bg, const float* __restrict__ bb, int writeScaled,
    int finalOut, const unsigned short* __restrict__ s1,
    const float* __restrict__ ue, const float* __restrict__ ie,
    float* __restrict__ outp) {
    int lane = threadIdx.x & 63;
    int lanelo = lane & 15;
    int quad = lane >> 4;
    int wid = (blockIdx.x * blockDim.x + threadIdx.x) >> 6;
    if (wid >= NTILES) return;

    // B-fragments from pre-converted bf16 W (vector loads, no conversion)
    short8 bWg[4][2], bWb[4][2];
#pragma unroll
    for (int t = 0; t < 4; ++t) {
#pragma unroll
        for (int h = 0; h < 2; ++h) {
            int n = t * 16 + lanelo;
            int k0 = h * 32 + quad * 8;
            bWg[t][h] = *(const short8*)&wgb[n * 64 + k0];
            bWb[t][h] = *(const short8*)&wbb[n * 64 + k0];
        }
    }
    float bgv[4], bbv[4];
#pragma unroll
    for (int t = 0; t < 4; ++t) {
        bgv[t] = bg[t * 16 + lanelo];
        bbv[t] = bb[t * 16 + lanelo];
    }

    int rbase = wid * 16;
    int arow = rbase + lanelo;
    short8 aG[2], aAG[2];
#pragma unroll
    for (int h = 0; h < 2; ++h) {
        uint4 ug = *(const uint4*)(gbuf + arow * 32 + h * 16 + quad * 4);
        uint4 ua = *(const uint4*)((const unsigned*)a_prev + arow * 32 + h * 16 + quad * 4);
        aG[h] = *(const short8*)&ug;
        uint4 up;
        up.x = pack_bf2(bf_lo(ua.x) * bf_lo(ug.x), bf_hi(ua.x) * bf_hi(ug.x));
        up.y = pack_bf2(bf_lo(ua.y) * bf_lo(ug.y), bf_hi(ua.y) * bf_hi(ug.y));
        up.z = pack_bf2(bf_lo(ua.z) * bf_lo(ug.z), bf_hi(ua.z) * bf_hi(ug.z));
        up.w = pack_bf2(bf_lo(ua.w) * bf_lo(ug.w), bf_hi(ua.w) * bf_hi(ug.w));
        aAG[h] = *(const short8*)&up;
    }
    floatx4 accg[4], accb[4];
#pragma unroll
    for (int t = 0; t < 4; ++t) {
        accg[t] = (floatx4)(0.f);
        accb[t] = (floatx4)(0.f);
    }
#pragma unroll
    for (int t = 0; t < 4; ++t) {
#pragma unroll
        for (int h = 0; h < 2; ++h) {
            accg[t] = __builtin_amdgcn_mfma_f32_16x16x32_bf16(aG[h], bWg[t][h], accg[t], 0, 0, 0);
            accb[t] = __builtin_amdgcn_mfma_f32_16x16x32_bf16(aAG[h], bWb[t][h], accb[t], 0, 0, 0);
        }
    }
    // epilogue in C/D layout: row = rbase + quad*4 + i, col = t*16 + lanelo
    float nv[4][4];
    float ss[4] = {0.f, 0.f, 0.f, 0.f};
#pragma unroll
    for (int i = 0; i < 4; ++i) {
        int r = rbase + quad * 4 + i;
#pragma unroll
        for (int t = 0; t < 4; ++t) {
            float a = __uint_as_float((unsigned)a_prev[r * 64 + t * 16 + lanelo] << 16);
            float e1 = accg[t][i] + bgv[t] + a;
            e1 = e1 >= 0.f ? e1 : 0.2f * e1;
            float e2 = accb[t][i] + bbv[t];
            e2 = e2 >= 0.f ? e2 : 0.2f * e2;
            float v = e1 + e2;
            nv[i][t] = v;
            ss[i] += v * v;
        }
    }
#pragma unroll
    for (int m = 1; m < 16; m <<= 1) {
#pragma unroll
        for (int i = 0; i < 4; ++i) ss[i] += __shfl_xor(ss[i], m, 64);
    }
#pragma unroll
    for (int i = 0; i < 4; ++i) {
        int r = rbase + quad * 4 + i;
        float rn = 1.0f / fmaxf(sqrtf(ss[i]), 1e-12f);
        float sc = isq[r] * rn;
        if (finalOut) {
#pragma unroll
            for (int t = 0; t < 4; ++t) {
                int idx = r * 64 + t * 16 + lanelo;
                float rr = nv[i][t] * rn;
                float s1v = __uint_as_float((unsigned)s1[idx] << 16);
                float s2v = __uint_as_float((unsigned)a_prev[idx] << 16);
                float ev = (r < NU) ? ue[idx] : ie[idx - NU * 64];
                outp[idx] = 0.25f * (ev + s1v + s2v + rr);
            }
        } else {
#pragma unroll
            for (int t = 0; t < 4; ++t) {
                int idx = r * 64 + t * 16 + lanelo;
                float rr = nv[i][t] * rn;
                snap_l[idx] = f2bf(rr);
                if (writeScaled)
                    ((unsigned short*)gbuf)[idx] = f2bf(nv[i][t] * sc);
            }
        }
    }
}

// ---------------- launch ----------------

extern "C" void kernel_launch(void* const* d_in, const int* in_sizes, int n_in,
                              void* d_out, int out_size, void* d_ws, size_t ws_size,
                              hipStream_t stream) {
    const float* u_emb = (const float*)d_in[0];
    const float* i_emb = (const float*)d_in[1];
    const float* Wgc = (const float*)d_in[2];
    const float* bgc = (const float*)d_in[3];
    const float* Wbi = (const float*)d_in[4];
    const float* bbi = (const float*)d_in[5];
    const int* edge_u = (const int*)d_in[6];
    const int* edge_i = (const int*)d_in[7];
    float* out = (float*)d_out;

    char* w = (char*)d_ws;
    auto alloc = [&](size_t bytes) {
        char* p = w;
        w += (bytes + 255) & ~(size_t)255;
        return p;
    };
    const size_t ROWBYTES = (size_t)(NTOT + 1) * EDIM * 2;   // +1 sentinel row
    int* deg = (int*)alloc((size_t)NTOT * 4);
    int* start = (int*)alloc((size_t)NTOT * 4);
    int* perm = (int*)alloc((size_t)NTOT * 4);
    unsigned* bcur = (unsigned*)alloc((size_t)NBKT * BCUR_STRIDE * 4);  // 16 KB
    int* csr = (int*)alloc((size_t)2 * NE * 4);
    float* isq = (float*)alloc((size_t)NTOT * 4);
    float* inv = (float*)alloc((size_t)NTOT * 4);
    unsigned short* wgb = (unsigned short*)alloc((size_t)NLAYERS * 4096 * 2);
    unsigned short* wbb = (unsigned short*)alloc((size_t)NLAYERS * 4096 * 2);
    unsigned* snap0 = (unsigned*)alloc((size_t)NTOT * EDIM * 2);
    unsigned* snap1 = (unsigned*)alloc((size_t)NTOT * EDIM * 2);
    unsigned* snap2 = (unsigned*)alloc((size_t)NTOT * EDIM * 2);
    unsigned* Ebuf = (unsigned*)alloc(ROWBYTES);
    unsigned* gbuf = (unsigned*)alloc(ROWBYTES);    // embS (in-place per layer)
    // packed pair bins (13.7 MB) alias snap1 (19.2 MB): bins are dead before
    // dense l=0 writes snap1.
    unsigned* bbuf = (unsigned*)snap1;

    // graph prep: two-level bin -> fused build (prefix+CSR+init+W+sentinel+perm)
    hipMemsetAsync(bcur, 0, (size_t)NBKT * BCUR_STRIDE * 4, stream);
    k_binpairs<<<BIN_NBLK, 256, 0, stream>>>(edge_u, edge_i, bcur, bbuf);
    k_buildcsr<<<NBKT, 1024, 0, stream>>>(bbuf, bcur, deg, start, isq, inv, csr,
                                          u_emb, i_emb, snap0, gbuf, Ebuf,
                                          Wgc, Wbi, wgb, wbb, perm);

    const int gatherBlocks = (NPAIR * 64 + 255) / 256;  // one wave per 2 rows
    const int denseBlocks = (NTILES * 64 + 255) / 256;  // one wave per 16-row tile
    const unsigned short* aprev[3] = {(unsigned short*)snap0, (unsigned short*)snap1,
                                      (unsigned short*)snap2};
    unsigned short* snaps[3] = {(unsigned short*)snap1, (unsigned short*)snap2,
                                (unsigned short*)snap1 /*unused for l=2*/};
    for (int l = 0; l < NLAYERS; ++l) {
        // E[n] = inv[n] * sum embS[m]      (embS = isq*emb, pre-scaled)
        k_gather<<<gatherBlocks, 256, 0, stream>>>(gbuf, Ebuf, csr, start, deg, inv, perm);
        // g[n] = isq[n] * sum E[m]
        k_gather<<<gatherBlocks, 256, 0, stream>>>(Ebuf, gbuf, csr, start, deg, isq, perm);
        k_dense_mfma<<<denseBlocks, 256, 0, stream>>>(
            aprev[l], gbuf, snaps[l], isq, wgb + (size_t)l * 4096, wbb + (size_t)l * 4096,
            bgc + (size_t)l * 64, bbi + (size_t)l * 64,
            l < NLAYERS - 1 ? 1 : 0,              // writeScaled
            l == NLAYERS - 1 ? 1 : 0,             // finalOut (fused k_out)
            (const unsigned short*)snap1, u_emb, i_emb, out);
    }
}

// Round 14
// 481.536 us; speedup vs baseline: 1.0260x; 1.0260x over previous
//
#include <hip/hip_runtime.h>
#include <cstdint>
#include <cstddef>

#define NU 100000
#define NI 50000
#define NTOT 150000
#define EDIM 64
#define NE 1000000
#define NLAYERS 3
#define NTILES (NTOT / 16)                            // 9375
#define NPAIR (NTOT / 2)                              // 75000 (gather: 2 rows/wave)

// ---- binned CSR build (two-level: LDS stage -> contiguous global chunks) ----
#define NBKT 256
#define NPB 586                    // nodes per bucket (256*586 = 150016 >= NTOT)
#define BCAP 13312                 // packed pairs per bucket; max expected ~12.1K
#define BCUR_STRIDE 16             // u32s -> 64B per cursor line
#define BIN_EPB 1024               // edges per binpairs block
#define BIN_NBLK ((NE + BIN_EPB - 1) / BIN_EPB)       // 977
#define LCAP 28                    // LDS pairs per bucket
#define LPAD 29                    // +1 pad -> conflict-free flush
#define SLICE_CAP 13312            // ints; max bucket pair-count ~12.1K

typedef __attribute__((ext_vector_type(8))) short short8;   // 8 bf16 (4 VGPRs)
typedef __attribute__((ext_vector_type(4))) float floatx4;  // 4 fp32 acc

// ---------------- bf16 helpers (raw-bit, RNE) ----------------
__device__ inline unsigned short f2bf(float f) {
    unsigned u = __float_as_uint(f);
    u += 0x7fffu + ((u >> 16) & 1u);
    return (unsigned short)(u >> 16);
}
__device__ inline unsigned pack_bf2(float a, float b) {
    unsigned ua = __float_as_uint(a); ua += 0x7fffu + ((ua >> 16) & 1u);
    unsigned ub = __float_as_uint(b); ub += 0x7fffu + ((ub >> 16) & 1u);
    return (ua >> 16) | (ub & 0xffff0000u);
}
__device__ inline float bf_lo(unsigned u) { return __uint_as_float(u << 16); }
__device__ inline float bf_hi(unsigned u) { return __uint_as_float(u & 0xffff0000u); }

// ---------------- phase A: two-level binning of packed (local,other) ----------------
// Pair word = (node - bucket*NPB) << 18 | other. LDS-staged per block, flushed
// as contiguous chunks (round-9 verified: this is the scatter-write fix).
__global__ __launch_bounds__(256) void k_binpairs(const int* __restrict__ eu,
                                                  const int* __restrict__ ei,
                                                  unsigned* __restrict__ bcur,
                                                  unsigned* __restrict__ bbuf) {
    __shared__ unsigned lbuf[NBKT * LPAD];   // 29.7 KB
    __shared__ int lcnt[NBKT];
    int t = threadIdx.x;
    if (t < NBKT) lcnt[t] = 0;
    __syncthreads();
    int ebase = blockIdx.x * BIN_EPB + t;
#pragma unroll
    for (int k = 0; k < 4; ++k) {
        int e = ebase + k * 256;
        if (e < NE) {
            int u = eu[e];
            int v = NU + ei[e];
            int b0 = u / NPB;
            int w0 = ((u - b0 * NPB) << 18) | v;
            int p0 = atomicAdd(&lcnt[b0], 1);
            if (p0 < LCAP) lbuf[b0 * LPAD + p0] = (unsigned)w0;
            else {
                unsigned gp = atomicAdd(&bcur[b0 * BCUR_STRIDE], 1u);
                if (gp < BCAP) bbuf[(size_t)b0 * BCAP + gp] = (unsigned)w0;
            }
            int b1 = v / NPB;
            int w1 = ((v - b1 * NPB) << 18) | u;
            int p1 = atomicAdd(&lcnt[b1], 1);
            if (p1 < LCAP) lbuf[b1 * LPAD + p1] = (unsigned)w1;
            else {
                unsigned gp = atomicAdd(&bcur[b1 * BCUR_STRIDE], 1u);
                if (gp < BCAP) bbuf[(size_t)b1 * BCAP + gp] = (unsigned)w1;
            }
        }
    }
    __syncthreads();
    // flush: thread t owns bucket t; one reservation, sequential chunk write
    int nb = min(lcnt[t], LCAP);
    if (nb > 0) {
        unsigned gp = atomicAdd(&bcur[t * BCUR_STRIDE], (unsigned)nb);
        for (int i = 0; i < nb; ++i) {
            unsigned idx = gp + i;
            if (idx < BCAP) bbuf[(size_t)t * BCAP + idx] = lbuf[t * LPAD + i];
        }
    }
}

// ---------------- phase B: per-bucket build (fused: prefix + deg/scan/CSR +
// init + W-conv + sentinel zero). One block per bucket. (Round-13's degree-
// sort perm REVERTED: it destroyed index-space locality, FETCH +5.5MB,
// gather +5.8us. Locality > load-balance for latency-bound gathers.)
__global__ __launch_bounds__(1024) void k_buildcsr(
    const unsigned* __restrict__ bbuf, const unsigned* __restrict__ bcur,
    int* __restrict__ deg, int* __restrict__ start,
    float* __restrict__ isq, float* __restrict__ inv, int* __restrict__ csr,
    const float* __restrict__ ue, const float* __restrict__ ie,
    unsigned* __restrict__ snap0, unsigned* __restrict__ gbuf,
    unsigned* __restrict__ Ebuf,
    const float* __restrict__ Wg, const float* __restrict__ Wb,
    unsigned short* __restrict__ wgb, unsigned short* __restrict__ wbb) {
    __shared__ int slice[SLICE_CAP];   // prefix temp, scan temp, then csr slice
    __shared__ int lcur[NPB];          // per-node count, then placement cursor
    __shared__ float sisq[NPB];
    __shared__ int bb_s, scnt_s;
    int b = blockIdx.x;
    int t = threadIdx.x;
    int n0 = b * NPB;
    int nn = NTOT - n0;
    if (nn > NPB) nn = NPB;
    if (nn < 0) nn = 0;
    // bucket-total prefix (redundant per block; 256 values, trivial)
    if (t < NBKT) slice[t] = min((int)bcur[t * BCUR_STRIDE], BCAP);
    if (t < NPB) lcur[t] = 0;
    __syncthreads();
    for (int off = 1; off < NBKT; off <<= 1) {
        int tmp = (t < NBKT && t >= off) ? slice[t - off] : 0;
        __syncthreads();
        if (t < NBKT) slice[t] += tmp;
        __syncthreads();
    }
    if (t == 0) {
        int tb = min((int)bcur[b * BCUR_STRIDE], BCAP);
        scnt_s = tb;
        bb_s = slice[b] - tb;   // exclusive prefix for this bucket
    }
    __syncthreads();
    int c = scnt_s;
    int bb = bb_s;
    const unsigned* pb = bbuf + (size_t)b * BCAP;
    // count pass
    for (int i = t; i < c; i += 1024) atomicAdd(&lcur[(int)(pb[i] >> 18)], 1);
    __syncthreads();
    // exclusive scan over nn counts (1024-wide Hillis-Steele in slice[])
    int cnt_t = (t < nn) ? lcur[t] : 0;
    slice[t] = cnt_t;
    __syncthreads();
    for (int off = 1; off < 1024; off <<= 1) {
        int tmp = (t >= off) ? slice[t - off] : 0;
        __syncthreads();
        slice[t] += tmp;
        __syncthreads();
    }
    int excl = slice[t] - cnt_t;
    int slen = slice[1023];            // total pairs in bucket
    if (t < nn) {
        int n = n0 + t;
        deg[n] = cnt_t;
        start[n] = bb + excl;
        float df = (float)cnt_t;
        float q = cnt_t > 0 ? 1.0f / sqrtf(df) : 0.f;
        isq[n] = q;
        sisq[t] = q;
        inv[n] = cnt_t > 0 ? 1.0f / df : 0.f;
    }
    __syncthreads();                   // everyone done reading slice & lcur
    if (t < nn) lcur[t] = excl;        // reuse as placement cursor
    __syncthreads();
    // place pass
    for (int i = t; i < c; i += 1024) {
        unsigned pr = pb[i];
        int idx = atomicAdd(&lcur[(int)(pr >> 18)], 1);
        if (idx < SLICE_CAP) slice[idx] = (int)(pr & 0x3FFFFu);
    }
    __syncthreads();
    if (slen > SLICE_CAP) slen = SLICE_CAP;
    for (int i = t; i < slen; i += 1024) csr[bb + i] = slice[i];
    // fused init: this bucket's rows -> snap0 (bf16) + gbuf (embS = isq*emb)
    for (int idx = t; idx < nn * 16; idx += 1024) {
        int r = idx >> 4, cc = idx & 15;
        int n = n0 + r;
        float4 v = (n < NU) ? ((const float4*)ue)[(size_t)n * 16 + cc]
                            : ((const float4*)ie)[(size_t)(n - NU) * 16 + cc];
        float s = sisq[r];
        uint2 bq, bs;
        bq.x = pack_bf2(v.x, v.y);
        bq.y = pack_bf2(v.z, v.w);
        bs.x = pack_bf2(v.x * s, v.y * s);
        bs.y = pack_bf2(v.z * s, v.w * s);
        ((uint2*)snap0)[(size_t)n * 16 + cc] = bq;
        ((uint2*)gbuf)[(size_t)n * 16 + cc] = bs;
    }
    // W conversion + sentinel-row zero: block 0 only
    if (b == 0) {
        for (int i = t; i < NLAYERS * 4096 / 4; i += 1024) {
            float4 g4 = ((const float4*)Wg)[i];
            float4 b4 = ((const float4*)Wb)[i];
            uint2 g, bq;
            g.x = pack_bf2(g4.x, g4.y); g.y = pack_bf2(g4.z, g4.w);
            bq.x = pack_bf2(b4.x, b4.y); bq.y = pack_bf2(b4.z, b4.w);
            ((uint2*)wgb)[i] = g;
            ((uint2*)wbb)[i] = bq;
        }
        if (t < 16) {
            ((uint2*)(Ebuf + NTOT * 32))[t] = make_uint2(0u, 0u);
            ((uint2*)(gbuf + NTOT * 32))[t] = make_uint2(0u, 0u);
        }
    }
}

// ---------------- sparse gather (pull), bf16 rows, wide loads ----------------
// v7 = v5 (round-12: natural row pairs 2gw/2gw+1, uint4 loads, 8 rows per
// instruction) + quantum-4 tail ONLY: slots padded to ceil-4 instead of
// ceil-16 (E[slots] ~23 -> ~18.3 for pair-max Poisson(13.3) degrees). No
// perm. Per-lane accumulation subsequence identical to v5; dropped sentinel
// slots contributed exact +0.0f -> bit-identical output.
__global__ __launch_bounds__(256) void k_gather(
    const unsigned* __restrict__ in_bf, unsigned* __restrict__ out_bf,
    const int* __restrict__ csr, const int* __restrict__ start,
    const int* __restrict__ deg, const float* __restrict__ sA) {
    int gw = (blockIdx.x * 256 + threadIdx.x) >> 6;   // wave id = row pair
    int lane = threadIdx.x & 63;
    if (gw >= NPAIR) return;
    int l2 = lane & 31;
    int hbase = lane & 32;                 // 0 or 32: this half's lane base
    int row = gw * 2 + (lane >> 5);
    int s = l2 & 7;                        // dword-quad owner (16B of the row)
    int g = l2 >> 3;                       // neighbor slot within batch (0..3)
    int s0 = start[row];
    int dg = deg[row];
    float sc = sA[row];                    // hoisted
    int dgo = __shfl_xor(dg, 32);          // other half's degree
    int dgmax = max(dg, dgo);              // uniform across the wave
    float aL0 = 0.f, aL1 = 0.f, aL2 = 0.f, aL3 = 0.f;
    float aH0 = 0.f, aH1 = 0.f, aH2 = 0.f, aH3 = 0.f;
    for (int j0 = 0; j0 < dgmax; j0 += 32) {
        int nidx = NTOT;                   // sentinel zero row
        if (j0 + l2 < dg) nidx = csr[s0 + j0 + l2];
        int jlim = min(32, dgmax - j0);
        int j = 0;
        for (; j + 16 <= jlim; j += 16) {
            // groups cover slots j..j+15 exactly once: j+4k+g, k=0..3
            int m0 = __shfl(nidx, hbase + j + g);
            int m1 = __shfl(nidx, hbase + j + 4 + g);
            int m2 = __shfl(nidx, hbase + j + 8 + g);
            int m3 = __shfl(nidx, hbase + j + 12 + g);
            uint4 u0 = *(const uint4*)(in_bf + (size_t)m0 * 32 + s * 4);
            uint4 u1 = *(const uint4*)(in_bf + (size_t)m1 * 32 + s * 4);
            uint4 u2 = *(const uint4*)(in_bf + (size_t)m2 * 32 + s * 4);
            uint4 u3 = *(const uint4*)(in_bf + (size_t)m3 * 32 + s * 4);
            aL0 += bf_lo(u0.x); aH0 += bf_hi(u0.x);
            aL1 += bf_lo(u0.y); aH1 += bf_hi(u0.y);
            aL2 += bf_lo(u0.z); aH2 += bf_hi(u0.z);
            aL3 += bf_lo(u0.w); aH3 += bf_hi(u0.w);
            aL0 += bf_lo(u1.x); aH0 += bf_hi(u1.x);
            aL1 += bf_lo(u1.y); aH1 += bf_hi(u1.y);
            aL2 += bf_lo(u1.z); aH2 += bf_hi(u1.z);
            aL3 += bf_lo(u1.w); aH3 += bf_hi(u1.w);
            aL0 += bf_lo(u2.x); aH0 += bf_hi(u2.x);
            aL1 += bf_lo(u2.y); aH1 += bf_hi(u2.y);
            aL2 += bf_lo(u2.z); aH2 += bf_hi(u2.z);
            aL3 += bf_lo(u2.w); aH3 += bf_hi(u2.w);
            aL0 += bf_lo(u3.x); aH0 += bf_hi(u3.x);
            aL1 += bf_lo(u3.y); aH1 += bf_hi(u3.y);
            aL2 += bf_lo(u3.z); aH2 += bf_hi(u3.z);
            aL3 += bf_lo(u3.w); aH3 += bf_hi(u3.w);
        }
        for (; j < jlim; j += 4) {         // quantum-4 tail (j <= 28, +g <= 31)
            int m0 = __shfl(nidx, hbase + j + g);
            uint4 u0 = *(const uint4*)(in_bf + (size_t)m0 * 32 + s * 4);
            aL0 += bf_lo(u0.x); aH0 += bf_hi(u0.x);
            aL1 += bf_lo(u0.y); aH1 += bf_hi(u0.y);
            aL2 += bf_lo(u0.z); aH2 += bf_hi(u0.z);
            aL3 += bf_lo(u0.w); aH3 += bf_hi(u0.w);
        }
    }
    // reduce the 4 group partials (lane bits 3 and 4; stays within the half)
#pragma unroll
    for (int m = 8; m <= 16; m <<= 1) {
        aL0 += __shfl_xor(aL0, m); aH0 += __shfl_xor(aH0, m);
        aL1 += __shfl_xor(aL1, m); aH1 += __shfl_xor(aH1, m);
        aL2 += __shfl_xor(aL2, m); aH2 += __shfl_xor(aH2, m);
        aL3 += __shfl_xor(aL3, m); aH3 += __shfl_xor(aH3, m);
    }
    if (g == 0) {
        uint4 o;
        o.x = pack_bf2(sc * aL0, sc * aH0);
        o.y = pack_bf2(sc * aL1, sc * aH1);
        o.z = pack_bf2(sc * aL2, sc * aH2);
        o.w = pack_bf2(sc * aL3, sc * aH3);
        *(uint4*)(out_bf + (size_t)row * 32 + s * 4) = o;
    }
}

// ---------------- dense per-row update via MFMA (all-bf16 state) ----------------
// One wave per 16-row tile. Reads g rows (from gbuf) + a rows (snap_prev).
// writeScaled: also write embS = isq*emb bf16 IN PLACE over gbuf. finalOut:
// fuse the output mean instead of writing snap_l. gbuf NOT __restrict__.
__global__ __launch_bounds__(256) void k_dense_mfma(
    const unsigned short* __restrict__ a_prev, unsigned* gbuf,
    unsigned short* __restrict__ snap_l, const float* __restrict__ isq,
    const unsigned short* __restrict__ wgb, const unsigned short* __restrict__ wbb,
    const float* __restrict__ bg, const float* __restrict__ bb, int writeScaled,
    int finalOut, const unsigned short* __restrict__ s1,
    const float* __restrict__ ue, const float* __restrict__ ie,
    float* __restrict__ outp) {
    int lane = threadIdx.x & 63;
    int lanelo = lane & 15;
    int quad = lane >> 4;
    int wid = (blockIdx.x * blockDim.x + threadIdx.x) >> 6;
    if (wid >= NTILES) return;

    // B-fragments from pre-converted bf16 W (vector loads, no conversion)
    short8 bWg[4][2], bWb[4][2];
#pragma unroll
    for (int t = 0; t < 4; ++t) {
#pragma unroll
        for (int h = 0; h < 2; ++h) {
            int n = t * 16 + lanelo;
            int k0 = h * 32 + quad * 8;
            bWg[t][h] = *(const short8*)&wgb[n * 64 + k0];
            bWb[t][h] = *(const short8*)&wbb[n * 64 + k0];
        }
    }
    float bgv[4], bbv[4];
#pragma unroll
    for (int t = 0; t < 4; ++t) {
        bgv[t] = bg[t * 16 + lanelo];
        bbv[t] = bb[t * 16 + lanelo];
    }

    int rbase = wid * 16;
    int arow = rbase + lanelo;
    short8 aG[2], aAG[2];
#pragma unroll
    for (int h = 0; h < 2; ++h) {
        uint4 ug = *(const uint4*)(gbuf + arow * 32 + h * 16 + quad * 4);
        uint4 ua = *(const uint4*)((const unsigned*)a_prev + arow * 32 + h * 16 + quad * 4);
        aG[h] = *(const short8*)&ug;
        uint4 up;
        up.x = pack_bf2(bf_lo(ua.x) * bf_lo(ug.x), bf_hi(ua.x) * bf_hi(ug.x));
        up.y = pack_bf2(bf_lo(ua.y) * bf_lo(ug.y), bf_hi(ua.y) * bf_hi(ug.y));
        up.z = pack_bf2(bf_lo(ua.z) * bf_lo(ug.z), bf_hi(ua.z) * bf_hi(ug.z));
        up.w = pack_bf2(bf_lo(ua.w) * bf_lo(ug.w), bf_hi(ua.w) * bf_hi(ug.w));
        aAG[h] = *(const short8*)&up;
    }
    floatx4 accg[4], accb[4];
#pragma unroll
    for (int t = 0; t < 4; ++t) {
        accg[t] = (floatx4)(0.f);
        accb[t] = (floatx4)(0.f);
    }
#pragma unroll
    for (int t = 0; t < 4; ++t) {
#pragma unroll
        for (int h = 0; h < 2; ++h) {
            accg[t] = __builtin_amdgcn_mfma_f32_16x16x32_bf16(aG[h], bWg[t][h], accg[t], 0, 0, 0);
            accb[t] = __builtin_amdgcn_mfma_f32_16x16x32_bf16(aAG[h], bWb[t][h], accb[t], 0, 0, 0);
        }
    }
    // epilogue in C/D layout: row = rbase + quad*4 + i, col = t*16 + lanelo
    float nv[4][4];
    float ss[4] = {0.f, 0.f, 0.f, 0.f};
#pragma unroll
    for (int i = 0; i < 4; ++i) {
        int r = rbase + quad * 4 + i;
#pragma unroll
        for (int t = 0; t < 4; ++t) {
            float a = __uint_as_float((unsigned)a_prev[r * 64 + t * 16 + lanelo] << 16);
            float e1 = accg[t][i] + bgv[t] + a;
            e1 = e1 >= 0.f ? e1 : 0.2f * e1;
            float e2 = accb[t][i] + bbv[t];
            e2 = e2 >= 0.f ? e2 : 0.2f * e2;
            float v = e1 + e2;
            nv[i][t] = v;
            ss[i] += v * v;
        }
    }
#pragma unroll
    for (int m = 1; m < 16; m <<= 1) {
#pragma unroll
        for (int i = 0; i < 4; ++i) ss[i] += __shfl_xor(ss[i], m, 64);
    }
#pragma unroll
    for (int i = 0; i < 4; ++i) {
        int r = rbase + quad * 4 + i;
        float rn = 1.0f / fmaxf(sqrtf(ss[i]), 1e-12f);
        float sc = isq[r] * rn;
        if (finalOut) {
#pragma unroll
            for (int t = 0; t < 4; ++t) {
                int idx = r * 64 + t * 16 + lanelo;
                float rr = nv[i][t] * rn;
                float s1v = __uint_as_float((unsigned)s1[idx] << 16);
                float s2v = __uint_as_float((unsigned)a_prev[idx] << 16);
                float ev = (r < NU) ? ue[idx] : ie[idx - NU * 64];
                outp[idx] = 0.25f * (ev + s1v + s2v + rr);
            }
        } else {
#pragma unroll
            for (int t = 0; t < 4; ++t) {
                int idx = r * 64 + t * 16 + lanelo;
                float rr = nv[i][t] * rn;
                snap_l[idx] = f2bf(rr);
                if (writeScaled)
                    ((unsigned short*)gbuf)[idx] = f2bf(nv[i][t] * sc);
            }
        }
    }
}

// ---------------- launch ----------------

extern "C" void kernel_launch(void* const* d_in, const int* in_sizes, int n_in,
                              void* d_out, int out_size, void* d_ws, size_t ws_size,
                              hipStream_t stream) {
    const float* u_emb = (const float*)d_in[0];
    const float* i_emb = (const float*)d_in[1];
    const float* Wgc = (const float*)d_in[2];
    const float* bgc = (const float*)d_in[3];
    const float* Wbi = (const float*)d_in[4];
    const float* bbi = (const float*)d_in[5];
    const int* edge_u = (const int*)d_in[6];
    const int* edge_i = (const int*)d_in[7];
    float* out = (float*)d_out;

    char* w = (char*)d_ws;
    auto alloc = [&](size_t bytes) {
        char* p = w;
        w += (bytes + 255) & ~(size_t)255;
        return p;
    };
    const size_t ROWBYTES = (size_t)(NTOT + 1) * EDIM * 2;   // +1 sentinel row
    int* deg = (int*)alloc((size_t)NTOT * 4);
    int* start = (int*)alloc((size_t)NTOT * 4);
    unsigned* bcur = (unsigned*)alloc((size_t)NBKT * BCUR_STRIDE * 4);  // 16 KB
    int* csr = (int*)alloc((size_t)2 * NE * 4);
    float* isq = (float*)alloc((size_t)NTOT * 4);
    float* inv = (float*)alloc((size_t)NTOT * 4);
    unsigned short* wgb = (unsigned short*)alloc((size_t)NLAYERS * 4096 * 2);
    unsigned short* wbb = (unsigned short*)alloc((size_t)NLAYERS * 4096 * 2);
    unsigned* snap0 = (unsigned*)alloc((size_t)NTOT * EDIM * 2);
    unsigned* snap1 = (unsigned*)alloc((size_t)NTOT * EDIM * 2);
    unsigned* snap2 = (unsigned*)alloc((size_t)NTOT * EDIM * 2);
    unsigned* Ebuf = (unsigned*)alloc(ROWBYTES);
    unsigned* gbuf = (unsigned*)alloc(ROWBYTES);    // embS (in-place per layer)
    // packed pair bins (13.7 MB) alias snap1 (19.2 MB): bins are dead before
    // dense l=0 writes snap1.
    unsigned* bbuf = (unsigned*)snap1;

    // graph prep: two-level bin -> fused build (prefix+CSR+init+W+sentinel)
    hipMemsetAsync(bcur, 0, (size_t)NBKT * BCUR_STRIDE * 4, stream);
    k_binpairs<<<BIN_NBLK, 256, 0, stream>>>(edge_u, edge_i, bcur, bbuf);
    k_buildcsr<<<NBKT, 1024, 0, stream>>>(bbuf, bcur, deg, start, isq, inv, csr,
                                          u_emb, i_emb, snap0, gbuf, Ebuf,
                                          Wgc, Wbi, wgb, wbb);

    const int gatherBlocks = (NPAIR * 64 + 255) / 256;  // one wave per 2 rows
    const int denseBlocks = (NTILES * 64 + 255) / 256;  // one wave per 16-row tile
    const unsigned short* aprev[3] = {(unsigned short*)snap0, (unsigned short*)snap1,
                                      (unsigned short*)snap2};
    unsigned short* snaps[3] = {(unsigned short*)snap1, (unsigned short*)snap2,
                                (unsigned short*)snap1 /*unused for l=2*/};
    for (int l = 0; l < NLAYERS; ++l) {
        // E[n] = inv[n] * sum embS[m]      (embS = isq*emb, pre-scaled)
        k_gather<<<gatherBlocks, 256, 0, stream>>>(gbuf, Ebuf, csr, start, deg, inv);
        // g[n] = isq[n] * sum E[m]
        k_gather<<<gatherBlocks, 256, 0, stream>>>(Ebuf, gbuf, csr, start, deg, isq);
        k_dense_mfma<<<denseBlocks, 256, 0, stream>>>(
            aprev[l], gbuf, snaps[l], isq, wgb + (size_t)l * 4096, wbb + (size_t)l * 4096,
            bgc + (size_t)l * 64, bbi + (size_t)l * 64,
            l < NLAYERS - 1 ? 1 : 0,              // writeScaled
            l == NLAYERS - 1 ? 1 : 0,             // finalOut (fused k_out)
            (const unsigned short*)snap1, u_emb, i_emb, out);
    }
}

// Round 15
// 458.089 us; speedup vs baseline: 1.0785x; 1.0512x over previous
//
#include <hip/hip_runtime.h>
#include <cstdint>
#include <cstddef>

#define NU 100000
#define NI 50000
#define NTOT 150000
#define EDIM 64
#define NE 1000000
#define NLAYERS 3
#define NTILES (NTOT / 16)                            // 9375
#define NPAIR (NTOT / 2)                              // 75000 (gather: 2 rows/wave)

// ---- binned CSR build (two-level: LDS stage -> contiguous global chunks) ----
#define NBKT 256
#define NPB 586                    // nodes per bucket (256*586 = 150016 >= NTOT)
#define BCAP 13312                 // packed pairs per bucket; max expected ~12.1K
#define BCUR_STRIDE 16             // u32s -> 64B per cursor line
#define BIN_EPB 1024               // edges per binpairs block
#define BIN_NBLK ((NE + BIN_EPB - 1) / BIN_EPB)       // 977
#define LCAP 28                    // LDS pairs per bucket
#define LPAD 29                    // +1 pad -> conflict-free flush
#define SLICE_CAP 13312            // ints; max bucket pair-count ~12.1K

typedef __attribute__((ext_vector_type(8))) short short8;   // 8 bf16 (4 VGPRs)
typedef __attribute__((ext_vector_type(4))) float floatx4;  // 4 fp32 acc

// ---------------- bf16 helpers (raw-bit, RNE) ----------------
__device__ inline unsigned short f2bf(float f) {
    unsigned u = __float_as_uint(f);
    u += 0x7fffu + ((u >> 16) & 1u);
    return (unsigned short)(u >> 16);
}
__device__ inline unsigned pack_bf2(float a, float b) {
    unsigned ua = __float_as_uint(a); ua += 0x7fffu + ((ua >> 16) & 1u);
    unsigned ub = __float_as_uint(b); ub += 0x7fffu + ((ub >> 16) & 1u);
    return (ua >> 16) | (ub & 0xffff0000u);
}
__device__ inline float bf_lo(unsigned u) { return __uint_as_float(u << 16); }
__device__ inline float bf_hi(unsigned u) { return __uint_as_float(u & 0xffff0000u); }

// ---------------- phase A: two-level binning of packed (local,other) ----------------
// Pair word = (node - bucket*NPB) << 18 | other. LDS-staged per block, flushed
// as contiguous chunks (round-9 verified: this is the scatter-write fix).
__global__ __launch_bounds__(256) void k_binpairs(const int* __restrict__ eu,
                                                  const int* __restrict__ ei,
                                                  unsigned* __restrict__ bcur,
                                                  unsigned* __restrict__ bbuf) {
    __shared__ unsigned lbuf[NBKT * LPAD];   // 29.7 KB
    __shared__ int lcnt[NBKT];
    int t = threadIdx.x;
    if (t < NBKT) lcnt[t] = 0;
    __syncthreads();
    int ebase = blockIdx.x * BIN_EPB + t;
#pragma unroll
    for (int k = 0; k < 4; ++k) {
        int e = ebase + k * 256;
        if (e < NE) {
            int u = eu[e];
            int v = NU + ei[e];
            int b0 = u / NPB;
            int w0 = ((u - b0 * NPB) << 18) | v;
            int p0 = atomicAdd(&lcnt[b0], 1);
            if (p0 < LCAP) lbuf[b0 * LPAD + p0] = (unsigned)w0;
            else {
                unsigned gp = atomicAdd(&bcur[b0 * BCUR_STRIDE], 1u);
                if (gp < BCAP) bbuf[(size_t)b0 * BCAP + gp] = (unsigned)w0;
            }
            int b1 = v / NPB;
            int w1 = ((v - b1 * NPB) << 18) | u;
            int p1 = atomicAdd(&lcnt[b1], 1);
            if (p1 < LCAP) lbuf[b1 * LPAD + p1] = (unsigned)w1;
            else {
                unsigned gp = atomicAdd(&bcur[b1 * BCUR_STRIDE], 1u);
                if (gp < BCAP) bbuf[(size_t)b1 * BCAP + gp] = (unsigned)w1;
            }
        }
    }
    __syncthreads();
    // flush: thread t owns bucket t; one reservation, sequential chunk write
    int nb = min(lcnt[t], LCAP);
    if (nb > 0) {
        unsigned gp = atomicAdd(&bcur[t * BCUR_STRIDE], (unsigned)nb);
        for (int i = 0; i < nb; ++i) {
            unsigned idx = gp + i;
            if (idx < BCAP) bbuf[(size_t)t * BCAP + idx] = lbuf[t * LPAD + i];
        }
    }
}

// ---------------- phase B: per-bucket build (fused: prefix + deg/scan/CSR +
// init + W-conv + sentinel zero). One block per bucket.
__global__ __launch_bounds__(1024) void k_buildcsr(
    const unsigned* __restrict__ bbuf, const unsigned* __restrict__ bcur,
    int* __restrict__ deg, int* __restrict__ start,
    float* __restrict__ isq, float* __restrict__ inv, int* __restrict__ csr,
    const float* __restrict__ ue, const float* __restrict__ ie,
    unsigned* __restrict__ snap0, unsigned* __restrict__ gbuf,
    unsigned* __restrict__ Ebuf,
    const float* __restrict__ Wg, const float* __restrict__ Wb,
    unsigned short* __restrict__ wgb, unsigned short* __restrict__ wbb) {
    __shared__ int slice[SLICE_CAP];   // prefix temp, scan temp, then csr slice
    __shared__ int lcur[NPB];          // per-node count, then placement cursor
    __shared__ float sisq[NPB];
    __shared__ int bb_s, scnt_s;
    int b = blockIdx.x;
    int t = threadIdx.x;
    int n0 = b * NPB;
    int nn = NTOT - n0;
    if (nn > NPB) nn = NPB;
    if (nn < 0) nn = 0;
    // bucket-total prefix (redundant per block; 256 values, trivial)
    if (t < NBKT) slice[t] = min((int)bcur[t * BCUR_STRIDE], BCAP);
    if (t < NPB) lcur[t] = 0;
    __syncthreads();
    for (int off = 1; off < NBKT; off <<= 1) {
        int tmp = (t < NBKT && t >= off) ? slice[t - off] : 0;
        __syncthreads();
        if (t < NBKT) slice[t] += tmp;
        __syncthreads();
    }
    if (t == 0) {
        int tb = min((int)bcur[b * BCUR_STRIDE], BCAP);
        scnt_s = tb;
        bb_s = slice[b] - tb;   // exclusive prefix for this bucket
    }
    __syncthreads();
    int c = scnt_s;
    int bb = bb_s;
    const unsigned* pb = bbuf + (size_t)b * BCAP;
    // count pass
    for (int i = t; i < c; i += 1024) atomicAdd(&lcur[(int)(pb[i] >> 18)], 1);
    __syncthreads();
    // exclusive scan over nn counts (1024-wide Hillis-Steele in slice[])
    int cnt_t = (t < nn) ? lcur[t] : 0;
    slice[t] = cnt_t;
    __syncthreads();
    for (int off = 1; off < 1024; off <<= 1) {
        int tmp = (t >= off) ? slice[t - off] : 0;
        __syncthreads();
        slice[t] += tmp;
        __syncthreads();
    }
    int excl = slice[t] - cnt_t;
    int slen = slice[1023];            // total pairs in bucket
    if (t < nn) {
        int n = n0 + t;
        deg[n] = cnt_t;
        start[n] = bb + excl;
        float df = (float)cnt_t;
        float q = cnt_t > 0 ? 1.0f / sqrtf(df) : 0.f;
        isq[n] = q;
        sisq[t] = q;
        inv[n] = cnt_t > 0 ? 1.0f / df : 0.f;
    }
    __syncthreads();                   // everyone done reading slice & lcur
    if (t < nn) lcur[t] = excl;        // reuse as placement cursor
    __syncthreads();
    // place pass
    for (int i = t; i < c; i += 1024) {
        unsigned pr = pb[i];
        int idx = atomicAdd(&lcur[(int)(pr >> 18)], 1);
        if (idx < SLICE_CAP) slice[idx] = (int)(pr & 0x3FFFFu);
    }
    __syncthreads();
    if (slen > SLICE_CAP) slen = SLICE_CAP;
    for (int i = t; i < slen; i += 1024) csr[bb + i] = slice[i];
    // fused init: this bucket's rows -> snap0 (bf16) + gbuf (embS = isq*emb)
    for (int idx = t; idx < nn * 16; idx += 1024) {
        int r = idx >> 4, cc = idx & 15;
        int n = n0 + r;
        float4 v = (n < NU) ? ((const float4*)ue)[(size_t)n * 16 + cc]
                            : ((const float4*)ie)[(size_t)(n - NU) * 16 + cc];
        float s = sisq[r];
        uint2 bq, bs;
        bq.x = pack_bf2(v.x, v.y);
        bq.y = pack_bf2(v.z, v.w);
        bs.x = pack_bf2(v.x * s, v.y * s);
        bs.y = pack_bf2(v.z * s, v.w * s);
        ((uint2*)snap0)[(size_t)n * 16 + cc] = bq;
        ((uint2*)gbuf)[(size_t)n * 16 + cc] = bs;
    }
    // W conversion + sentinel-row zero: block 0 only
    if (b == 0) {
        for (int i = t; i < NLAYERS * 4096 / 4; i += 1024) {
            float4 g4 = ((const float4*)Wg)[i];
            float4 b4 = ((const float4*)Wb)[i];
            uint2 g, bq;
            g.x = pack_bf2(g4.x, g4.y); g.y = pack_bf2(g4.z, g4.w);
            bq.x = pack_bf2(b4.x, b4.y); bq.y = pack_bf2(b4.z, b4.w);
            ((uint2*)wgb)[i] = g;
            ((uint2*)wbb)[i] = bq;
        }
        if (t < 16) {
            ((uint2*)(Ebuf + NTOT * 32))[t] = make_uint2(0u, 0u);
            ((uint2*)(gbuf + NTOT * 32))[t] = make_uint2(0u, 0u);
        }
    }
}

// ---------------- sparse gather (pull), bf16 rows, wide loads ----------------
// v5 EXACT (round-12 verified best): natural row pairs 2gw/2gw+1, uint4 loads
// (one instruction fetches 8 neighbor rows), fixed 16-slot inner blocks.
// Round-13 perm (locality loss) and round-14 quantum-4 tail (broke unrolled
// load issue) both REVERTED per counters.
__global__ __launch_bounds__(256) void k_gather(
    const unsigned* __restrict__ in_bf, unsigned* __restrict__ out_bf,
    const int* __restrict__ csr, const int* __restrict__ start,
    const int* __restrict__ deg, const float* __restrict__ sA) {
    int gw = (blockIdx.x * 256 + threadIdx.x) >> 6;   // wave id = row pair
    int lane = threadIdx.x & 63;
    if (gw >= NPAIR) return;
    int l2 = lane & 31;
    int hbase = lane & 32;                 // 0 or 32: this half's lane base
    int row = gw * 2 + (lane >> 5);
    int s = l2 & 7;                        // dword-quad owner (16B of the row)
    int g = l2 >> 3;                       // neighbor slot within batch (0..3)
    int s0 = start[row];
    int dg = deg[row];
    float sc = sA[row];                    // hoisted
    int dgo = __shfl_xor(dg, 32);          // other half's degree
    int dgmax = max(dg, dgo);              // uniform across the wave
    float aL0 = 0.f, aL1 = 0.f, aL2 = 0.f, aL3 = 0.f;
    float aH0 = 0.f, aH1 = 0.f, aH2 = 0.f, aH3 = 0.f;
    for (int j0 = 0; j0 < dgmax; j0 += 32) {
        int nidx = NTOT;                   // sentinel zero row
        if (j0 + l2 < dg) nidx = csr[s0 + j0 + l2];
        int jlim = min(32, dgmax - j0);
        for (int j = 0; j < jlim; j += 16) {
            // groups cover slots j..j+15 exactly once: j+4k+g, k=0..3
            int m0 = __shfl(nidx, hbase + j + g);
            int m1 = __shfl(nidx, hbase + j + 4 + g);
            int m2 = __shfl(nidx, hbase + j + 8 + g);
            int m3 = __shfl(nidx, hbase + j + 12 + g);
            uint4 u0 = *(const uint4*)(in_bf + (size_t)m0 * 32 + s * 4);
            uint4 u1 = *(const uint4*)(in_bf + (size_t)m1 * 32 + s * 4);
            uint4 u2 = *(const uint4*)(in_bf + (size_t)m2 * 32 + s * 4);
            uint4 u3 = *(const uint4*)(in_bf + (size_t)m3 * 32 + s * 4);
            aL0 += bf_lo(u0.x); aH0 += bf_hi(u0.x);
            aL1 += bf_lo(u0.y); aH1 += bf_hi(u0.y);
            aL2 += bf_lo(u0.z); aH2 += bf_hi(u0.z);
            aL3 += bf_lo(u0.w); aH3 += bf_hi(u0.w);
            aL0 += bf_lo(u1.x); aH0 += bf_hi(u1.x);
            aL1 += bf_lo(u1.y); aH1 += bf_hi(u1.y);
            aL2 += bf_lo(u1.z); aH2 += bf_hi(u1.z);
            aL3 += bf_lo(u1.w); aH3 += bf_hi(u1.w);
            aL0 += bf_lo(u2.x); aH0 += bf_hi(u2.x);
            aL1 += bf_lo(u2.y); aH1 += bf_hi(u2.y);
            aL2 += bf_lo(u2.z); aH2 += bf_hi(u2.z);
            aL3 += bf_lo(u2.w); aH3 += bf_hi(u2.w);
            aL0 += bf_lo(u3.x); aH0 += bf_hi(u3.x);
            aL1 += bf_lo(u3.y); aH1 += bf_hi(u3.y);
            aL2 += bf_lo(u3.z); aH2 += bf_hi(u3.z);
            aL3 += bf_lo(u3.w); aH3 += bf_hi(u3.w);
        }
    }
    // reduce the 4 group partials (lane bits 3 and 4; stays within the half)
#pragma unroll
    for (int m = 8; m <= 16; m <<= 1) {
        aL0 += __shfl_xor(aL0, m); aH0 += __shfl_xor(aH0, m);
        aL1 += __shfl_xor(aL1, m); aH1 += __shfl_xor(aH1, m);
        aL2 += __shfl_xor(aL2, m); aH2 += __shfl_xor(aH2, m);
        aL3 += __shfl_xor(aL3, m); aH3 += __shfl_xor(aH3, m);
    }
    if (g == 0) {
        uint4 o;
        o.x = pack_bf2(sc * aL0, sc * aH0);
        o.y = pack_bf2(sc * aL1, sc * aH1);
        o.z = pack_bf2(sc * aL2, sc * aH2);
        o.w = pack_bf2(sc * aL3, sc * aH3);
        *(uint4*)(out_bf + (size_t)row * 32 + s * 4) = o;
    }
}

// ---------------- dense per-row update via MFMA (all-bf16 state) ----------------
// Round 15: epilogue layout conversion via SELECTOR MFMA. The wave already
// holds the a_prev (and for finalOut, snap1) tile in fragment registers;
// D = A * Sel with Sel[k][n] = (k == sel*16+n) delivers A[:, t*16..+16] in
// C/D layout BIT-EXACTLY (single nonzero product, bf16*1.0 in f32). Replaces
// 16 scalar u16 global re-loads per lane (+~12MB FETCH) with 4 MFMAs.
__global__ __launch_bounds__(256) void k_dense_mfma(
    const unsigned short* __restrict__ a_prev, unsigned* gbuf,
    unsigned short* __restrict__ snap_l, const float* __restrict__ isq,
    const unsigned short* __restrict__ wgb, const unsigned short* __restrict__ wbb,
    const float* __restrict__ bg, const float* __restrict__ bb, int writeScaled,
    int finalOut, const unsigned short* __restrict__ s1,
    const float* __restrict__ ue, const float* __restrict__ ie,
    float* __restrict__ outp) {
    int lane = threadIdx.x & 63;
    int lanelo = lane & 15;
    int quad = lane >> 4;
    int wid = (blockIdx.x * blockDim.x + threadIdx.x) >> 6;
    if (wid >= NTILES) return;

    // selector B-fragments: Sel[sel] with B[k'][n] = (k' == sel*16 + n).
    // B-fragment element jj at lane (lanelo,quad) covers (n=lanelo, k'=quad*8+jj).
    short8 selF[2];
#pragma unroll
    for (int sel = 0; sel < 2; ++sel) {
#pragma unroll
        for (int jj = 0; jj < 8; ++jj)
            selF[sel][jj] = (quad * 8 + jj == sel * 16 + lanelo)
                                ? (short)0x3F80 : (short)0;   // bf16 1.0
    }

    // B-fragments from pre-converted bf16 W (vector loads, no conversion)
    short8 bWg[4][2], bWb[4][2];
#pragma unroll
    for (int t = 0; t < 4; ++t) {
#pragma unroll
        for (int h = 0; h < 2; ++h) {
            int n = t * 16 + lanelo;
            int k0 = h * 32 + quad * 8;
            bWg[t][h] = *(const short8*)&wgb[n * 64 + k0];
            bWb[t][h] = *(const short8*)&wbb[n * 64 + k0];
        }
    }
    float bgv[4], bbv[4];
#pragma unroll
    for (int t = 0; t < 4; ++t) {
        bgv[t] = bg[t * 16 + lanelo];
        bbv[t] = bb[t * 16 + lanelo];
    }

    int rbase = wid * 16;
    int arow = rbase + lanelo;
    short8 aG[2], aAG[2], aA[2];
#pragma unroll
    for (int h = 0; h < 2; ++h) {
        uint4 ug = *(const uint4*)(gbuf + arow * 32 + h * 16 + quad * 4);
        uint4 ua = *(const uint4*)((const unsigned*)a_prev + arow * 32 + h * 16 + quad * 4);
        aG[h] = *(const short8*)&ug;
        aA[h] = *(const short8*)&ua;
        uint4 up;
        up.x = pack_bf2(bf_lo(ua.x) * bf_lo(ug.x), bf_hi(ua.x) * bf_hi(ug.x));
        up.y = pack_bf2(bf_lo(ua.y) * bf_lo(ug.y), bf_hi(ua.y) * bf_hi(ug.y));
        up.z = pack_bf2(bf_lo(ua.z) * bf_lo(ug.z), bf_hi(ua.z) * bf_hi(ug.z));
        up.w = pack_bf2(bf_lo(ua.w) * bf_lo(ug.w), bf_hi(ua.w) * bf_hi(ug.w));
        aAG[h] = *(const short8*)&up;
    }
    floatx4 accg[4], accb[4], accA[4];
#pragma unroll
    for (int t = 0; t < 4; ++t) {
        accg[t] = (floatx4)(0.f);
        accb[t] = (floatx4)(0.f);
    }
#pragma unroll
    for (int t = 0; t < 4; ++t) {
#pragma unroll
        for (int h = 0; h < 2; ++h) {
            accg[t] = __builtin_amdgcn_mfma_f32_16x16x32_bf16(aG[h], bWg[t][h], accg[t], 0, 0, 0);
            accb[t] = __builtin_amdgcn_mfma_f32_16x16x32_bf16(aAG[h], bWb[t][h], accb[t], 0, 0, 0);
        }
        // layout-convert a_prev col group t into C/D (bit-exact)
        accA[t] = __builtin_amdgcn_mfma_f32_16x16x32_bf16(
            aA[t >> 1], selF[t & 1], (floatx4)(0.f), 0, 0, 0);
    }
    floatx4 accS[4];
    if (finalOut) {
        short8 s1A[2];
#pragma unroll
        for (int h = 0; h < 2; ++h) {
            uint4 us = *(const uint4*)((const unsigned*)s1 + arow * 32 + h * 16 + quad * 4);
            s1A[h] = *(const short8*)&us;
        }
#pragma unroll
        for (int t = 0; t < 4; ++t)
            accS[t] = __builtin_amdgcn_mfma_f32_16x16x32_bf16(
                s1A[t >> 1], selF[t & 1], (floatx4)(0.f), 0, 0, 0);
    }
    // epilogue in C/D layout: row = rbase + quad*4 + i, col = t*16 + lanelo
    float nv[4][4];
    float ss[4] = {0.f, 0.f, 0.f, 0.f};
#pragma unroll
    for (int i = 0; i < 4; ++i) {
#pragma unroll
        for (int t = 0; t < 4; ++t) {
            float a = accA[t][i];
            float e1 = accg[t][i] + bgv[t] + a;
            e1 = e1 >= 0.f ? e1 : 0.2f * e1;
            float e2 = accb[t][i] + bbv[t];
            e2 = e2 >= 0.f ? e2 : 0.2f * e2;
            float v = e1 + e2;
            nv[i][t] = v;
            ss[i] += v * v;
        }
    }
#pragma unroll
    for (int m = 1; m < 16; m <<= 1) {
#pragma unroll
        for (int i = 0; i < 4; ++i) ss[i] += __shfl_xor(ss[i], m, 64);
    }
#pragma unroll
    for (int i = 0; i < 4; ++i) {
        int r = rbase + quad * 4 + i;
        float rn = 1.0f / fmaxf(sqrtf(ss[i]), 1e-12f);
        float sc = isq[r] * rn;
        if (finalOut) {
#pragma unroll
            for (int t = 0; t < 4; ++t) {
                int idx = r * 64 + t * 16 + lanelo;
                float rr = nv[i][t] * rn;
                float s1v = accS[t][i];
                float s2v = accA[t][i];
                float ev = (r < NU) ? ue[idx] : ie[idx - NU * 64];
                outp[idx] = 0.25f * (ev + s1v + s2v + rr);
            }
        } else {
#pragma unroll
            for (int t = 0; t < 4; ++t) {
                int idx = r * 64 + t * 16 + lanelo;
                float rr = nv[i][t] * rn;
                snap_l[idx] = f2bf(rr);
                if (writeScaled)
                    ((unsigned short*)gbuf)[idx] = f2bf(nv[i][t] * sc);
            }
        }
    }
}

// ---------------- launch ----------------

extern "C" void kernel_launch(void* const* d_in, const int* in_sizes, int n_in,
                              void* d_out, int out_size, void* d_ws, size_t ws_size,
                              hipStream_t stream) {
    const float* u_emb = (const float*)d_in[0];
    const float* i_emb = (const float*)d_in[1];
    const float* Wgc = (const float*)d_in[2];
    const float* bgc = (const float*)d_in[3];
    const float* Wbi = (const float*)d_in[4];
    const float* bbi = (const float*)d_in[5];
    const int* edge_u = (const int*)d_in[6];
    const int* edge_i = (const int*)d_in[7];
    float* out = (float*)d_out;

    char* w = (char*)d_ws;
    auto alloc = [&](size_t bytes) {
        char* p = w;
        w += (bytes + 255) & ~(size_t)255;
        return p;
    };
    const size_t ROWBYTES = (size_t)(NTOT + 1) * EDIM * 2;   // +1 sentinel row
    int* deg = (int*)alloc((size_t)NTOT * 4);
    int* start = (int*)alloc((size_t)NTOT * 4);
    unsigned* bcur = (unsigned*)alloc((size_t)NBKT * BCUR_STRIDE * 4);  // 16 KB
    int* csr = (int*)alloc((size_t)2 * NE * 4);
    float* isq = (float*)alloc((size_t)NTOT * 4);
    float* inv = (float*)alloc((size_t)NTOT * 4);
    unsigned short* wgb = (unsigned short*)alloc((size_t)NLAYERS * 4096 * 2);
    unsigned short* wbb = (unsigned short*)alloc((size_t)NLAYERS * 4096 * 2);
    unsigned* snap0 = (unsigned*)alloc((size_t)NTOT * EDIM * 2);
    unsigned* snap1 = (unsigned*)alloc((size_t)NTOT * EDIM * 2);
    unsigned* snap2 = (unsigned*)alloc((size_t)NTOT * EDIM * 2);
    unsigned* Ebuf = (unsigned*)alloc(ROWBYTES);
    unsigned* gbuf = (unsigned*)alloc(ROWBYTES);    // embS (in-place per layer)
    // packed pair bins (13.7 MB) alias snap1 (19.2 MB): bins are dead before
    // dense l=0 writes snap1.
    unsigned* bbuf = (unsigned*)snap1;

    // graph prep: two-level bin -> fused build (prefix+CSR+init+W+sentinel)
    hipMemsetAsync(bcur, 0, (size_t)NBKT * BCUR_STRIDE * 4, stream);
    k_binpairs<<<BIN_NBLK, 256, 0, stream>>>(edge_u, edge_i, bcur, bbuf);
    k_buildcsr<<<NBKT, 1024, 0, stream>>>(bbuf, bcur, deg, start, isq, inv, csr,
                                          u_emb, i_emb, snap0, gbuf, Ebuf,
                                          Wgc, Wbi, wgb, wbb);

    const int gatherBlocks = (NPAIR * 64 + 255) / 256;  // one wave per 2 rows
    const int denseBlocks = (NTILES * 64 + 255) / 256;  // one wave per 16-row tile
    const unsigned short* aprev[3] = {(unsigned short*)snap0, (unsigned short*)snap1,
                                      (unsigned short*)snap2};
    unsigned short* snaps[3] = {(unsigned short*)snap1, (unsigned short*)snap2,
                                (unsigned short*)snap1 /*unused for l=2*/};
    for (int l = 0; l < NLAYERS; ++l) {
        // E[n] = inv[n] * sum embS[m]      (embS = isq*emb, pre-scaled)
        k_gather<<<gatherBlocks, 256, 0, stream>>>(gbuf, Ebuf, csr, start, deg, inv);
        // g[n] = isq[n] * sum E[m]
        k_gather<<<gatherBlocks, 256, 0, stream>>>(Ebuf, gbuf, csr, start, deg, isq);
        k_dense_mfma<<<denseBlocks, 256, 0, stream>>>(
            aprev[l], gbuf, snaps[l], isq, wgb + (size_t)l * 4096, wbb + (size_t)l * 4096,
            bgc + (size_t)l * 64, bbi + (size_t)l * 64,
            l < NLAYERS - 1 ? 1 : 0,              // writeScaled
            l == NLAYERS - 1 ? 1 : 0,             // finalOut (fused k_out)
            (const unsigned short*)snap1, u_emb, i_emb, out);
    }
}

// Round 16
// 453.658 us; speedup vs baseline: 1.0891x; 1.0098x over previous
//
#include <hip/hip_runtime.h>
#include <cstdint>
#include <cstddef>

#define NU 100000
#define NI 50000
#define NTOT 150000
#define EDIM 64
#define NE 1000000
#define NLAYERS 3
#define NTILES (NTOT / 16)                            // 9375
#define NPAIR (NTOT / 2)                              // 75000 (gather: 2 rows/wave)
#define DTILE 2                                       // dense: tiles per wave
#define NDW ((NTILES + DTILE - 1) / DTILE)            // 4688 dense waves

// ---- binned CSR build (two-level: LDS stage -> contiguous global chunks) ----
#define NBKT 256
#define NPB 586                    // nodes per bucket (256*586 = 150016 >= NTOT)
#define BCAP 13312                 // packed pairs per bucket; max expected ~12.1K
#define BCUR_STRIDE 16             // u32s -> 64B per cursor line
#define BIN_EPB 1024               // edges per binpairs block
#define BIN_NBLK ((NE + BIN_EPB - 1) / BIN_EPB)       // 977
#define LCAP 28                    // LDS pairs per bucket
#define LPAD 29                    // +1 pad -> conflict-free flush
#define SLICE_CAP 13312            // ints; max bucket pair-count ~12.1K

typedef __attribute__((ext_vector_type(8))) short short8;   // 8 bf16 (4 VGPRs)
typedef __attribute__((ext_vector_type(4))) float floatx4;  // 4 fp32 acc

// ---------------- bf16 helpers (raw-bit, RNE) ----------------
__device__ inline unsigned short f2bf(float f) {
    unsigned u = __float_as_uint(f);
    u += 0x7fffu + ((u >> 16) & 1u);
    return (unsigned short)(u >> 16);
}
__device__ inline unsigned pack_bf2(float a, float b) {
    unsigned ua = __float_as_uint(a); ua += 0x7fffu + ((ua >> 16) & 1u);
    unsigned ub = __float_as_uint(b); ub += 0x7fffu + ((ub >> 16) & 1u);
    return (ua >> 16) | (ub & 0xffff0000u);
}
__device__ inline float bf_lo(unsigned u) { return __uint_as_float(u << 16); }
__device__ inline float bf_hi(unsigned u) { return __uint_as_float(u & 0xffff0000u); }

// ---------------- phase A: two-level binning of packed (local,other) ----------------
// Pair word = (node - bucket*NPB) << 18 | other. LDS-staged per block, flushed
// as contiguous chunks (round-9 verified: this is the scatter-write fix).
__global__ __launch_bounds__(256) void k_binpairs(const int* __restrict__ eu,
                                                  const int* __restrict__ ei,
                                                  unsigned* __restrict__ bcur,
                                                  unsigned* __restrict__ bbuf) {
    __shared__ unsigned lbuf[NBKT * LPAD];   // 29.7 KB
    __shared__ int lcnt[NBKT];
    int t = threadIdx.x;
    if (t < NBKT) lcnt[t] = 0;
    __syncthreads();
    int ebase = blockIdx.x * BIN_EPB + t;
#pragma unroll
    for (int k = 0; k < 4; ++k) {
        int e = ebase + k * 256;
        if (e < NE) {
            int u = eu[e];
            int v = NU + ei[e];
            int b0 = u / NPB;
            int w0 = ((u - b0 * NPB) << 18) | v;
            int p0 = atomicAdd(&lcnt[b0], 1);
            if (p0 < LCAP) lbuf[b0 * LPAD + p0] = (unsigned)w0;
            else {
                unsigned gp = atomicAdd(&bcur[b0 * BCUR_STRIDE], 1u);
                if (gp < BCAP) bbuf[(size_t)b0 * BCAP + gp] = (unsigned)w0;
            }
            int b1 = v / NPB;
            int w1 = ((v - b1 * NPB) << 18) | u;
            int p1 = atomicAdd(&lcnt[b1], 1);
            if (p1 < LCAP) lbuf[b1 * LPAD + p1] = (unsigned)w1;
            else {
                unsigned gp = atomicAdd(&bcur[b1 * BCUR_STRIDE], 1u);
                if (gp < BCAP) bbuf[(size_t)b1 * BCAP + gp] = (unsigned)w1;
            }
        }
    }
    __syncthreads();
    // flush: thread t owns bucket t; one reservation, sequential chunk write
    int nb = min(lcnt[t], LCAP);
    if (nb > 0) {
        unsigned gp = atomicAdd(&bcur[t * BCUR_STRIDE], (unsigned)nb);
        for (int i = 0; i < nb; ++i) {
            unsigned idx = gp + i;
            if (idx < BCAP) bbuf[(size_t)t * BCAP + idx] = lbuf[t * LPAD + i];
        }
    }
}

// ---------------- phase B: per-bucket build (fused: prefix + deg/scan/CSR +
// init + W-conv + sentinel zero). One block per bucket.
__global__ __launch_bounds__(1024) void k_buildcsr(
    const unsigned* __restrict__ bbuf, const unsigned* __restrict__ bcur,
    int* __restrict__ deg, int* __restrict__ start,
    float* __restrict__ isq, float* __restrict__ inv, int* __restrict__ csr,
    const float* __restrict__ ue, const float* __restrict__ ie,
    unsigned* __restrict__ snap0, unsigned* __restrict__ gbuf,
    unsigned* __restrict__ Ebuf,
    const float* __restrict__ Wg, const float* __restrict__ Wb,
    unsigned short* __restrict__ wgb, unsigned short* __restrict__ wbb) {
    __shared__ int slice[SLICE_CAP];   // prefix temp, scan temp, then csr slice
    __shared__ int lcur[NPB];          // per-node count, then placement cursor
    __shared__ float sisq[NPB];
    __shared__ int bb_s, scnt_s;
    int b = blockIdx.x;
    int t = threadIdx.x;
    int n0 = b * NPB;
    int nn = NTOT - n0;
    if (nn > NPB) nn = NPB;
    if (nn < 0) nn = 0;
    // bucket-total prefix (redundant per block; 256 values, trivial)
    if (t < NBKT) slice[t] = min((int)bcur[t * BCUR_STRIDE], BCAP);
    if (t < NPB) lcur[t] = 0;
    __syncthreads();
    for (int off = 1; off < NBKT; off <<= 1) {
        int tmp = (t < NBKT && t >= off) ? slice[t - off] : 0;
        __syncthreads();
        if (t < NBKT) slice[t] += tmp;
        __syncthreads();
    }
    if (t == 0) {
        int tb = min((int)bcur[b * BCUR_STRIDE], BCAP);
        scnt_s = tb;
        bb_s = slice[b] - tb;   // exclusive prefix for this bucket
    }
    __syncthreads();
    int c = scnt_s;
    int bb = bb_s;
    const unsigned* pb = bbuf + (size_t)b * BCAP;
    // count pass
    for (int i = t; i < c; i += 1024) atomicAdd(&lcur[(int)(pb[i] >> 18)], 1);
    __syncthreads();
    // exclusive scan over nn counts (1024-wide Hillis-Steele in slice[])
    int cnt_t = (t < nn) ? lcur[t] : 0;
    slice[t] = cnt_t;
    __syncthreads();
    for (int off = 1; off < 1024; off <<= 1) {
        int tmp = (t >= off) ? slice[t - off] : 0;
        __syncthreads();
        slice[t] += tmp;
        __syncthreads();
    }
    int excl = slice[t] - cnt_t;
    int slen = slice[1023];            // total pairs in bucket
    if (t < nn) {
        int n = n0 + t;
        deg[n] = cnt_t;
        start[n] = bb + excl;
        float df = (float)cnt_t;
        float q = cnt_t > 0 ? 1.0f / sqrtf(df) : 0.f;
        isq[n] = q;
        sisq[t] = q;
        inv[n] = cnt_t > 0 ? 1.0f / df : 0.f;
    }
    __syncthreads();                   // everyone done reading slice & lcur
    if (t < nn) lcur[t] = excl;        // reuse as placement cursor
    __syncthreads();
    // place pass
    for (int i = t; i < c; i += 1024) {
        unsigned pr = pb[i];
        int idx = atomicAdd(&lcur[(int)(pr >> 18)], 1);
        if (idx < SLICE_CAP) slice[idx] = (int)(pr & 0x3FFFFu);
    }
    __syncthreads();
    if (slen > SLICE_CAP) slen = SLICE_CAP;
    for (int i = t; i < slen; i += 1024) csr[bb + i] = slice[i];
    // fused init: this bucket's rows -> snap0 (bf16) + gbuf (embS = isq*emb)
    for (int idx = t; idx < nn * 16; idx += 1024) {
        int r = idx >> 4, cc = idx & 15;
        int n = n0 + r;
        float4 v = (n < NU) ? ((const float4*)ue)[(size_t)n * 16 + cc]
                            : ((const float4*)ie)[(size_t)(n - NU) * 16 + cc];
        float s = sisq[r];
        uint2 bq, bs;
        bq.x = pack_bf2(v.x, v.y);
        bq.y = pack_bf2(v.z, v.w);
        bs.x = pack_bf2(v.x * s, v.y * s);
        bs.y = pack_bf2(v.z * s, v.w * s);
        ((uint2*)snap0)[(size_t)n * 16 + cc] = bq;
        ((uint2*)gbuf)[(size_t)n * 16 + cc] = bs;
    }
    // W conversion + sentinel-row zero: block 0 only
    if (b == 0) {
        for (int i = t; i < NLAYERS * 4096 / 4; i += 1024) {
            float4 g4 = ((const float4*)Wg)[i];
            float4 b4 = ((const float4*)Wb)[i];
            uint2 g, bq;
            g.x = pack_bf2(g4.x, g4.y); g.y = pack_bf2(g4.z, g4.w);
            bq.x = pack_bf2(b4.x, b4.y); bq.y = pack_bf2(b4.z, b4.w);
            ((uint2*)wgb)[i] = g;
            ((uint2*)wbb)[i] = bq;
        }
        if (t < 16) {
            ((uint2*)(Ebuf + NTOT * 32))[t] = make_uint2(0u, 0u);
            ((uint2*)(gbuf + NTOT * 32))[t] = make_uint2(0u, 0u);
        }
    }
}

// ---------------- sparse gather (pull), bf16 rows, wide loads ----------------
// v5 EXACT (round-12 verified best): natural row pairs 2gw/2gw+1, uint4 loads
// (one instruction fetches 8 neighbor rows), fixed 16-slot inner blocks.
__global__ __launch_bounds__(256) void k_gather(
    const unsigned* __restrict__ in_bf, unsigned* __restrict__ out_bf,
    const int* __restrict__ csr, const int* __restrict__ start,
    const int* __restrict__ deg, const float* __restrict__ sA) {
    int gw = (blockIdx.x * 256 + threadIdx.x) >> 6;   // wave id = row pair
    int lane = threadIdx.x & 63;
    if (gw >= NPAIR) return;
    int l2 = lane & 31;
    int hbase = lane & 32;                 // 0 or 32: this half's lane base
    int row = gw * 2 + (lane >> 5);
    int s = l2 & 7;                        // dword-quad owner (16B of the row)
    int g = l2 >> 3;                       // neighbor slot within batch (0..3)
    int s0 = start[row];
    int dg = deg[row];
    float sc = sA[row];                    // hoisted
    int dgo = __shfl_xor(dg, 32);          // other half's degree
    int dgmax = max(dg, dgo);              // uniform across the wave
    float aL0 = 0.f, aL1 = 0.f, aL2 = 0.f, aL3 = 0.f;
    float aH0 = 0.f, aH1 = 0.f, aH2 = 0.f, aH3 = 0.f;
    for (int j0 = 0; j0 < dgmax; j0 += 32) {
        int nidx = NTOT;                   // sentinel zero row
        if (j0 + l2 < dg) nidx = csr[s0 + j0 + l2];
        int jlim = min(32, dgmax - j0);
        for (int j = 0; j < jlim; j += 16) {
            // groups cover slots j..j+15 exactly once: j+4k+g, k=0..3
            int m0 = __shfl(nidx, hbase + j + g);
            int m1 = __shfl(nidx, hbase + j + 4 + g);
            int m2 = __shfl(nidx, hbase + j + 8 + g);
            int m3 = __shfl(nidx, hbase + j + 12 + g);
            uint4 u0 = *(const uint4*)(in_bf + (size_t)m0 * 32 + s * 4);
            uint4 u1 = *(const uint4*)(in_bf + (size_t)m1 * 32 + s * 4);
            uint4 u2 = *(const uint4*)(in_bf + (size_t)m2 * 32 + s * 4);
            uint4 u3 = *(const uint4*)(in_bf + (size_t)m3 * 32 + s * 4);
            aL0 += bf_lo(u0.x); aH0 += bf_hi(u0.x);
            aL1 += bf_lo(u0.y); aH1 += bf_hi(u0.y);
            aL2 += bf_lo(u0.z); aH2 += bf_hi(u0.z);
            aL3 += bf_lo(u0.w); aH3 += bf_hi(u0.w);
            aL0 += bf_lo(u1.x); aH0 += bf_hi(u1.x);
            aL1 += bf_lo(u1.y); aH1 += bf_hi(u1.y);
            aL2 += bf_lo(u1.z); aH2 += bf_hi(u1.z);
            aL3 += bf_lo(u1.w); aH3 += bf_hi(u1.w);
            aL0 += bf_lo(u2.x); aH0 += bf_hi(u2.x);
            aL1 += bf_lo(u2.y); aH1 += bf_hi(u2.y);
            aL2 += bf_lo(u2.z); aH2 += bf_hi(u2.z);
            aL3 += bf_lo(u2.w); aH3 += bf_hi(u2.w);
            aL0 += bf_lo(u3.x); aH0 += bf_hi(u3.x);
            aL1 += bf_lo(u3.y); aH1 += bf_hi(u3.y);
            aL2 += bf_lo(u3.z); aH2 += bf_hi(u3.z);
            aL3 += bf_lo(u3.w); aH3 += bf_hi(u3.w);
        }
    }
    // reduce the 4 group partials (lane bits 3 and 4; stays within the half)
#pragma unroll
    for (int m = 8; m <= 16; m <<= 1) {
        aL0 += __shfl_xor(aL0, m); aH0 += __shfl_xor(aH0, m);
        aL1 += __shfl_xor(aL1, m); aH1 += __shfl_xor(aH1, m);
        aL2 += __shfl_xor(aL2, m); aH2 += __shfl_xor(aH2, m);
        aL3 += __shfl_xor(aL3, m); aH3 += __shfl_xor(aH3, m);
    }
    if (g == 0) {
        uint4 o;
        o.x = pack_bf2(sc * aL0, sc * aH0);
        o.y = pack_bf2(sc * aL1, sc * aH1);
        o.z = pack_bf2(sc * aL2, sc * aH2);
        o.w = pack_bf2(sc * aL3, sc * aH3);
        *(uint4*)(out_bf + (size_t)row * 32 + s * 4) = o;
    }
}

// ---------------- dense per-row update via MFMA (all-bf16 state) ----------------
// Round 16: MULTI-TILE (DTILE=2). Each wave owns two ADJACENT 16-row tiles;
// W/selector/bias fragments load once per wave (halves the ~150MB L2 W
// traffic and per-tile setup latency); the independent tiles give cross-tile
// ILP (tile-1 loads overlap tile-0 epilogue). Per-tile math unchanged
// (round-15 selector-MFMA epilogue, bit-exact).
__global__ __launch_bounds__(256) void k_dense_mfma(
    const unsigned short* __restrict__ a_prev, unsigned* gbuf,
    unsigned short* __restrict__ snap_l, const float* __restrict__ isq,
    const unsigned short* __restrict__ wgb, const unsigned short* __restrict__ wbb,
    const float* __restrict__ bg, const float* __restrict__ bb, int writeScaled,
    int finalOut, const unsigned short* __restrict__ s1,
    const float* __restrict__ ue, const float* __restrict__ ie,
    float* __restrict__ outp) {
    int lane = threadIdx.x & 63;
    int lanelo = lane & 15;
    int quad = lane >> 4;
    int wv = (blockIdx.x * blockDim.x + threadIdx.x) >> 6;
    if (wv >= NDW) return;

    // selector B-fragments: Sel[sel] with B[k'][n] = (k' == sel*16 + n).
    short8 selF[2];
#pragma unroll
    for (int sel = 0; sel < 2; ++sel) {
#pragma unroll
        for (int jj = 0; jj < 8; ++jj)
            selF[sel][jj] = (quad * 8 + jj == sel * 16 + lanelo)
                                ? (short)0x3F80 : (short)0;   // bf16 1.0
    }

    // B-fragments from pre-converted bf16 W (once per wave, reused per tile)
    short8 bWg[4][2], bWb[4][2];
#pragma unroll
    for (int t = 0; t < 4; ++t) {
#pragma unroll
        for (int h = 0; h < 2; ++h) {
            int n = t * 16 + lanelo;
            int k0 = h * 32 + quad * 8;
            bWg[t][h] = *(const short8*)&wgb[n * 64 + k0];
            bWb[t][h] = *(const short8*)&wbb[n * 64 + k0];
        }
    }
    float bgv[4], bbv[4];
#pragma unroll
    for (int t = 0; t < 4; ++t) {
        bgv[t] = bg[t * 16 + lanelo];
        bbv[t] = bb[t * 16 + lanelo];
    }

#pragma unroll
    for (int tt = 0; tt < DTILE; ++tt) {
        int wid = wv * DTILE + tt;
        if (wid >= NTILES) break;
        int rbase = wid * 16;
        int arow = rbase + lanelo;
        short8 aG[2], aAG[2], aA[2];
#pragma unroll
        for (int h = 0; h < 2; ++h) {
            uint4 ug = *(const uint4*)(gbuf + arow * 32 + h * 16 + quad * 4);
            uint4 ua = *(const uint4*)((const unsigned*)a_prev + arow * 32 + h * 16 + quad * 4);
            aG[h] = *(const short8*)&ug;
            aA[h] = *(const short8*)&ua;
            uint4 up;
            up.x = pack_bf2(bf_lo(ua.x) * bf_lo(ug.x), bf_hi(ua.x) * bf_hi(ug.x));
            up.y = pack_bf2(bf_lo(ua.y) * bf_lo(ug.y), bf_hi(ua.y) * bf_hi(ug.y));
            up.z = pack_bf2(bf_lo(ua.z) * bf_lo(ug.z), bf_hi(ua.z) * bf_hi(ug.z));
            up.w = pack_bf2(bf_lo(ua.w) * bf_lo(ug.w), bf_hi(ua.w) * bf_hi(ug.w));
            aAG[h] = *(const short8*)&up;
        }
        floatx4 accg[4], accb[4], accA[4];
#pragma unroll
        for (int t = 0; t < 4; ++t) {
            accg[t] = (floatx4)(0.f);
            accb[t] = (floatx4)(0.f);
        }
#pragma unroll
        for (int t = 0; t < 4; ++t) {
#pragma unroll
            for (int h = 0; h < 2; ++h) {
                accg[t] = __builtin_amdgcn_mfma_f32_16x16x32_bf16(aG[h], bWg[t][h], accg[t], 0, 0, 0);
                accb[t] = __builtin_amdgcn_mfma_f32_16x16x32_bf16(aAG[h], bWb[t][h], accb[t], 0, 0, 0);
            }
            // layout-convert a_prev col group t into C/D (bit-exact)
            accA[t] = __builtin_amdgcn_mfma_f32_16x16x32_bf16(
                aA[t >> 1], selF[t & 1], (floatx4)(0.f), 0, 0, 0);
        }
        floatx4 accS[4];
        if (finalOut) {
            short8 s1A[2];
#pragma unroll
            for (int h = 0; h < 2; ++h) {
                uint4 us = *(const uint4*)((const unsigned*)s1 + arow * 32 + h * 16 + quad * 4);
                s1A[h] = *(const short8*)&us;
            }
#pragma unroll
            for (int t = 0; t < 4; ++t)
                accS[t] = __builtin_amdgcn_mfma_f32_16x16x32_bf16(
                    s1A[t >> 1], selF[t & 1], (floatx4)(0.f), 0, 0, 0);
        }
        // epilogue in C/D layout: row = rbase + quad*4 + i, col = t*16 + lanelo
        float nv[4][4];
        float ss[4] = {0.f, 0.f, 0.f, 0.f};
#pragma unroll
        for (int i = 0; i < 4; ++i) {
#pragma unroll
            for (int t = 0; t < 4; ++t) {
                float a = accA[t][i];
                float e1 = accg[t][i] + bgv[t] + a;
                e1 = e1 >= 0.f ? e1 : 0.2f * e1;
                float e2 = accb[t][i] + bbv[t];
                e2 = e2 >= 0.f ? e2 : 0.2f * e2;
                float v = e1 + e2;
                nv[i][t] = v;
                ss[i] += v * v;
            }
        }
#pragma unroll
        for (int m = 1; m < 16; m <<= 1) {
#pragma unroll
            for (int i = 0; i < 4; ++i) ss[i] += __shfl_xor(ss[i], m, 64);
        }
#pragma unroll
        for (int i = 0; i < 4; ++i) {
            int r = rbase + quad * 4 + i;
            float rn = 1.0f / fmaxf(sqrtf(ss[i]), 1e-12f);
            float sc = isq[r] * rn;
            if (finalOut) {
#pragma unroll
                for (int t = 0; t < 4; ++t) {
                    int idx = r * 64 + t * 16 + lanelo;
                    float rr = nv[i][t] * rn;
                    float s1v = accS[t][i];
                    float s2v = accA[t][i];
                    float ev = (r < NU) ? ue[idx] : ie[idx - NU * 64];
                    outp[idx] = 0.25f * (ev + s1v + s2v + rr);
                }
            } else {
#pragma unroll
                for (int t = 0; t < 4; ++t) {
                    int idx = r * 64 + t * 16 + lanelo;
                    float rr = nv[i][t] * rn;
                    snap_l[idx] = f2bf(rr);
                    if (writeScaled)
                        ((unsigned short*)gbuf)[idx] = f2bf(nv[i][t] * sc);
                }
            }
        }
    }
}

// ---------------- launch ----------------

extern "C" void kernel_launch(void* const* d_in, const int* in_sizes, int n_in,
                              void* d_out, int out_size, void* d_ws, size_t ws_size,
                              hipStream_t stream) {
    const float* u_emb = (const float*)d_in[0];
    const float* i_emb = (const float*)d_in[1];
    const float* Wgc = (const float*)d_in[2];
    const float* bgc = (const float*)d_in[3];
    const float* Wbi = (const float*)d_in[4];
    const float* bbi = (const float*)d_in[5];
    const int* edge_u = (const int*)d_in[6];
    const int* edge_i = (const int*)d_in[7];
    float* out = (float*)d_out;

    char* w = (char*)d_ws;
    auto alloc = [&](size_t bytes) {
        char* p = w;
        w += (bytes + 255) & ~(size_t)255;
        return p;
    };
    const size_t ROWBYTES = (size_t)(NTOT + 1) * EDIM * 2;   // +1 sentinel row
    int* deg = (int*)alloc((size_t)NTOT * 4);
    int* start = (int*)alloc((size_t)NTOT * 4);
    unsigned* bcur = (unsigned*)alloc((size_t)NBKT * BCUR_STRIDE * 4);  // 16 KB
    int* csr = (int*)alloc((size_t)2 * NE * 4);
    float* isq = (float*)alloc((size_t)NTOT * 4);
    float* inv = (float*)alloc((size_t)NTOT * 4);
    unsigned short* wgb = (unsigned short*)alloc((size_t)NLAYERS * 4096 * 2);
    unsigned short* wbb = (unsigned short*)alloc((size_t)NLAYERS * 4096 * 2);
    unsigned* snap0 = (unsigned*)alloc((size_t)NTOT * EDIM * 2);
    unsigned* snap1 = (unsigned*)alloc((size_t)NTOT * EDIM * 2);
    unsigned* snap2 = (unsigned*)alloc((size_t)NTOT * EDIM * 2);
    unsigned* Ebuf = (unsigned*)alloc(ROWBYTES);
    unsigned* gbuf = (unsigned*)alloc(ROWBYTES);    // embS (in-place per layer)
    // packed pair bins (13.7 MB) alias snap1 (19.2 MB): bins are dead before
    // dense l=0 writes snap1.
    unsigned* bbuf = (unsigned*)snap1;

    // graph prep: two-level bin -> fused build (prefix+CSR+init+W+sentinel)
    hipMemsetAsync(bcur, 0, (size_t)NBKT * BCUR_STRIDE * 4, stream);
    k_binpairs<<<BIN_NBLK, 256, 0, stream>>>(edge_u, edge_i, bcur, bbuf);
    k_buildcsr<<<NBKT, 1024, 0, stream>>>(bbuf, bcur, deg, start, isq, inv, csr,
                                          u_emb, i_emb, snap0, gbuf, Ebuf,
                                          Wgc, Wbi, wgb, wbb);

    const int gatherBlocks = (NPAIR * 64 + 255) / 256;  // one wave per 2 rows
    const int denseBlocks = (NDW * 64 + 255) / 256;     // one wave per 2 tiles
    const unsigned short* aprev[3] = {(unsigned short*)snap0, (unsigned short*)snap1,
                                      (unsigned short*)snap2};
    unsigned short* snaps[3] = {(unsigned short*)snap1, (unsigned short*)snap2,
                                (unsigned short*)snap1 /*unused for l=2*/};
    for (int l = 0; l < NLAYERS; ++l) {
        // E[n] = inv[n] * sum embS[m]      (embS = isq*emb, pre-scaled)
        k_gather<<<gatherBlocks, 256, 0, stream>>>(gbuf, Ebuf, csr, start, deg, inv);
        // g[n] = isq[n] * sum E[m]
        k_gather<<<gatherBlocks, 256, 0, stream>>>(Ebuf, gbuf, csr, start, deg, isq);
        k_dense_mfma<<<denseBlocks, 256, 0, stream>>>(
            aprev[l], gbuf, snaps[l], isq, wgb + (size_t)l * 4096, wbb + (size_t)l * 4096,
            bgc + (size_t)l * 64, bbi + (size_t)l * 64,
            l < NLAYERS - 1 ? 1 : 0,              // writeScaled
            l == NLAYERS - 1 ? 1 : 0,             // finalOut (fused k_out)
            (const unsigned short*)snap1, u_emb, i_emb, out);
    }
}